// Round 1
// baseline (3571.728 us; speedup 1.0000x reference)
//
#include <hip/hip_runtime.h>
#include <math.h>

typedef unsigned long long u64;

#define D   256
#define NT  32          // nodes per block in k_scores
#define PT  64          // pooled rows per block in k_xpool
#define ECH 16          // edges per thread
#define EBLK (256*ECH)  // edges per block

__device__ __forceinline__ double lrelu(double v){ return v > 0.0 ? v : 0.2*v; }
__device__ __forceinline__ float  lreluf(float v){ return v > 0.0f ? v : 0.2f*v; }

// ---------------- degree ----------------
__global__ void k_degree(const int* __restrict__ row, int E, int* __restrict__ deg){
  int stride = gridDim.x*blockDim.x;
  for (int i = blockIdx.x*blockDim.x + threadIdx.x; i < E; i += stride)
    atomicAdd(&deg[row[i]], 1);
}

__global__ void k_degsq(const int* __restrict__ deg, int N, u64* __restrict__ out){
  __shared__ u64 sh[256];
  u64 local = 0;
  int stride = gridDim.x*blockDim.x;
  for (int i = blockIdx.x*blockDim.x + threadIdx.x; i < N; i += stride){
    u64 d = (u64)deg[i];
    local += d*d;
  }
  sh[threadIdx.x] = local; __syncthreads();
  for (int s = 128; s > 0; s >>= 1){
    if (threadIdx.x < s) sh[threadIdx.x] += sh[threadIdx.x+s];
    __syncthreads();
  }
  if (threadIdx.x == 0) atomicAdd(out, sh[0]);
}

// s1b[j] = sum_{r=256..511} w_s1[r][j]  (bottom-half column sums), plus scalar weights
__global__ void k_prep(const float* __restrict__ wS1, const float* __restrict__ alpha,
                       const float* __restrict__ beta, const u64* __restrict__ sumsq,
                       double* __restrict__ s1b, double* __restrict__ scal){
  int j = threadIdx.x;
  double s = 0.0;
  for (int r = 0; r < D; ++r) s += (double)wS1[(D + r)*D + j];
  s1b[j] = s;
  if (j == 0){
    double a = 1.0/(1.0 + exp(-(double)alpha[0]));
    double b = 1.0/(1.0 + exp(-(double)beta[0]));
    scal[0] = a/(a+b);
    scal[1] = b/(a+b);
    double dn = sqrt((double)(*sumsq));
    scal[2] = dn > 1e-12 ? dn : 1e-12;
  }
}

// ---------------- scores (f64) ----------------
__global__ __launch_bounds__(256) void k_scores(
    const float* __restrict__ x,
    const int*   __restrict__ deg,
    const float* __restrict__ wS1, const float* __restrict__ bS1,
    const float* __restrict__ wS2, const float* __restrict__ bS2,
    const float* __restrict__ wF1, const float* __restrict__ bF1,
    const float* __restrict__ wF2, const float* __restrict__ bF2,
    const double* __restrict__ s1b, const double* __restrict__ scal,
    double* __restrict__ scores, int N)
{
  __shared__ double xs[NT][D];        // 64 KiB, f64 to avoid per-FMA cvt
  __shared__ double dnorm[NT];
  __shared__ double red4[4][NT];
  __shared__ double structS[NT];
  __shared__ double bbuf[128][8];

  const int tid = threadIdx.x;
  const int node0 = blockIdx.x * NT;
  const int nn = min(NT, N - node0);

  for (int t = tid; t < NT*D; t += 256){
    int n = t >> 8;
    int c = t & (D-1);
    int node = node0 + n;
    xs[n][c] = (node < N) ? (double)x[(size_t)node*D + c] : 0.0;
  }
  if (tid < NT){
    int node = node0 + tid;
    dnorm[tid] = (node < N) ? ((double)deg[node] / scal[2]) : 0.0;
  }
  __syncthreads();

  // ---- phase A: t1 = x@W_s1_top + dn*s1b + b_s1 ; struct = sum lrelu(t1)*w_s2 ----
  const int j = tid;
  double acc[NT];
  {
    const double b0 = (double)bS1[j];
    const double sb = s1b[j];
    #pragma unroll
    for (int n = 0; n < NT; ++n) acc[n] = fma(dnorm[n], sb, b0);
  }
  #pragma unroll 2
  for (int r = 0; r < D; r += 4){
    const double w0 = (double)wS1[(r+0)*D + j];
    const double w1 = (double)wS1[(r+1)*D + j];
    const double w2 = (double)wS1[(r+2)*D + j];
    const double w3 = (double)wS1[(r+3)*D + j];
    #pragma unroll
    for (int n = 0; n < NT; ++n){
      double2 a01 = *reinterpret_cast<const double2*>(&xs[n][r]);
      double2 a23 = *reinterpret_cast<const double2*>(&xs[n][r+2]);
      acc[n] = fma(a01.x, w0, acc[n]);
      acc[n] = fma(a01.y, w1, acc[n]);
      acc[n] = fma(a23.x, w2, acc[n]);
      acc[n] = fma(a23.y, w3, acc[n]);
    }
  }
  {
    const double w2j = (double)wS2[j];
    const int wave = tid >> 6, lane = tid & 63;
    #pragma unroll
    for (int n = 0; n < NT; ++n){
      double v = lrelu(acc[n]) * w2j;
      v += __shfl_down(v, 32);
      v += __shfl_down(v, 16);
      v += __shfl_down(v, 8);
      v += __shfl_down(v, 4);
      v += __shfl_down(v, 2);
      v += __shfl_down(v, 1);
      if (lane == 0) red4[wave][n] = v;
    }
  }
  __syncthreads();
  if (tid < NT)
    structS[tid] = red4[0][tid] + red4[1][tid] + red4[2][tid] + red4[3][tid] + (double)bS2[0];

  // ---- phase B: t2 = x@W_f1 + b_f1 ; feat = sum lrelu(t2)*w_f2 (rows split in halves) ----
  const int jb = tid & 127;
  const int half = tid >> 7;
  const int r0 = half * 128;
  double acc2[NT];
  {
    const double b0 = half ? 0.0 : (double)bF1[jb];
    #pragma unroll
    for (int n = 0; n < NT; ++n) acc2[n] = b0;
  }
  #pragma unroll 2
  for (int r = 0; r < 128; r += 4){
    const double w0 = (double)wF1[(r0+r+0)*128 + jb];
    const double w1 = (double)wF1[(r0+r+1)*128 + jb];
    const double w2 = (double)wF1[(r0+r+2)*128 + jb];
    const double w3 = (double)wF1[(r0+r+3)*128 + jb];
    #pragma unroll
    for (int n = 0; n < NT; ++n){
      double2 a01 = *reinterpret_cast<const double2*>(&xs[n][r0+r]);
      double2 a23 = *reinterpret_cast<const double2*>(&xs[n][r0+r+2]);
      acc2[n] = fma(a01.x, w0, acc2[n]);
      acc2[n] = fma(a01.y, w1, acc2[n]);
      acc2[n] = fma(a23.x, w2, acc2[n]);
      acc2[n] = fma(a23.y, w3, acc2[n]);
    }
  }
  __syncthreads();      // structS consumed red4; safe to reuse LDS now
  #pragma unroll
  for (int c = 0; c < NT; c += 8){
    if (half){
      #pragma unroll
      for (int q = 0; q < 8; ++q) bbuf[jb][q] = acc2[c+q];
    }
    __syncthreads();
    if (!half){
      #pragma unroll
      for (int q = 0; q < 8; ++q) acc2[c+q] += bbuf[jb][q];
    }
    __syncthreads();
  }
  {
    const double w2j = (double)wF2[jb];
    const int wave = tid >> 6, lane = tid & 63;
    #pragma unroll
    for (int n = 0; n < NT; ++n){
      double v = (half == 0) ? (lrelu(acc2[n]) * w2j) : 0.0;
      v += __shfl_down(v, 32);
      v += __shfl_down(v, 16);
      v += __shfl_down(v, 8);
      v += __shfl_down(v, 4);
      v += __shfl_down(v, 2);
      v += __shfl_down(v, 1);
      if (lane == 0) red4[wave][n] = v;
    }
  }
  __syncthreads();
  if (tid < nn){
    double feat = red4[0][tid] + red4[1][tid] + (double)bF2[0];
    scores[node0 + tid] = scal[0]*structS[tid] + scal[1]*feat;
  }
}

// ---------------- top-k via bitonic sort (desc score, asc idx) ----------------
__global__ void k_build_keys(const double* __restrict__ scores, int N, int SORTN,
                             u64* __restrict__ keys, int* __restrict__ idxs){
  int i = blockIdx.x*blockDim.x + threadIdx.x;
  if (i >= SORTN) return;
  u64 kk;
  if (i < N){
    u64 u = (u64)__double_as_longlong(scores[i]);
    u = (u >> 63) ? ~u : (u | 0x8000000000000000ULL);  // ascending in score
    kk = ~u;                                           // ascending key = descending score
  } else {
    kk = 0xFFFFFFFFFFFFFFFFULL;                        // pad sorts last
  }
  keys[i] = kk;
  idxs[i] = i;
}

__device__ __forceinline__ bool kgreater(u64 ka, int ia, u64 kb, int ib){
  return (ka > kb) || (ka == kb && ia > ib);
}

__global__ __launch_bounds__(1024) void k_bsort_local(u64* __restrict__ keys, int* __restrict__ idxs){
  __shared__ u64 sk[2048];
  __shared__ int si[2048];
  const int tid = threadIdx.x;
  const int base = blockIdx.x * 2048;
  sk[tid] = keys[base+tid]; sk[tid+1024] = keys[base+tid+1024];
  si[tid] = idxs[base+tid]; si[tid+1024] = idxs[base+tid+1024];
  __syncthreads();
  for (int size = 2; size <= 2048; size <<= 1){
    for (int stride = size >> 1; stride > 0; stride >>= 1){
      int i  = 2*tid - (tid & (stride-1));
      int jj = i + stride;
      bool up = (((base + i) & size) == 0);
      u64 ki = sk[i], kj = sk[jj];
      int ii = si[i], ij = si[jj];
      if (kgreater(ki, ii, kj, ij) == up){
        sk[i] = kj; sk[jj] = ki; si[i] = ij; si[jj] = ii;
      }
      __syncthreads();
    }
  }
  keys[base+tid] = sk[tid]; keys[base+tid+1024] = sk[tid+1024];
  idxs[base+tid] = si[tid]; idxs[base+tid+1024] = si[tid+1024];
}

__global__ void k_bpass(u64* __restrict__ keys, int* __restrict__ idxs, int size, int stride){
  int t  = blockIdx.x*blockDim.x + threadIdx.x;
  int i  = 2*t - (t & (stride-1));
  int jj = i + stride;
  bool up = ((i & size) == 0);
  u64 ki = keys[i], kj = keys[jj];
  int ii = idxs[i], ij = idxs[jj];
  if (kgreater(ki, ii, kj, ij) == up){
    keys[i] = kj; keys[jj] = ki; idxs[i] = ij; idxs[jj] = ii;
  }
}

__global__ __launch_bounds__(1024) void k_bmerge_local(u64* __restrict__ keys, int* __restrict__ idxs, int size){
  __shared__ u64 sk[2048];
  __shared__ int si[2048];
  const int tid = threadIdx.x;
  const int base = blockIdx.x * 2048;
  sk[tid] = keys[base+tid]; sk[tid+1024] = keys[base+tid+1024];
  si[tid] = idxs[base+tid]; si[tid+1024] = idxs[base+tid+1024];
  __syncthreads();
  for (int stride = 1024; stride > 0; stride >>= 1){
    int i  = 2*tid - (tid & (stride-1));
    int jj = i + stride;
    bool up = (((base + i) & size) == 0);
    u64 ki = sk[i], kj = sk[jj];
    int ii = si[i], ij = si[jj];
    if (kgreater(ki, ii, kj, ij) == up){
      sk[i] = kj; sk[jj] = ki; si[i] = ij; si[jj] = ii;
    }
    __syncthreads();
  }
  keys[base+tid] = sk[tid]; keys[base+tid+1024] = sk[tid+1024];
  idxs[base+tid] = si[tid]; idxs[base+tid+1024] = si[tid+1024];
}

// ---------------- post-topk outputs ----------------
__global__ void k_nodemap_set(const int* __restrict__ idxs, int k, int* __restrict__ nmap){
  int p = blockIdx.x*blockDim.x + threadIdx.x;
  if (p < k) nmap[idxs[p]] = p;
}

__global__ void k_topk_out(const double* __restrict__ scores, const int* __restrict__ idxs,
                           int k, float* __restrict__ outS){
  int p = blockIdx.x*blockDim.x + threadIdx.x;
  if (p < k) outS[p] = (float)scores[idxs[p]];
}

__global__ __launch_bounds__(256) void k_xpool(const float* __restrict__ x, const int* __restrict__ idxs,
    const float* __restrict__ wP, const float* __restrict__ bP, float* __restrict__ out, int kk){
  __shared__ float xp[PT][D];   // 64 KiB
  const int tid = threadIdx.x;
  const int p0 = blockIdx.x * PT;
  if (p0 >= kk) return;
  const int rows = min(PT, kk - p0);
  for (int t = tid; t < PT*D; t += 256){
    int n = t >> 8, c = t & (D-1);
    int p = p0 + n; if (p >= kk) p = kk - 1;
    xp[n][c] = x[(size_t)idxs[p]*D + c];
  }
  __syncthreads();
  const int j = tid;
  float acc[PT];
  const float b = bP[j];
  #pragma unroll
  for (int n = 0; n < PT; ++n) acc[n] = b;
  #pragma unroll 2
  for (int r = 0; r < D; r += 4){
    float w0 = wP[(r+0)*D + j];
    float w1 = wP[(r+1)*D + j];
    float w2 = wP[(r+2)*D + j];
    float w3 = wP[(r+3)*D + j];
    #pragma unroll
    for (int n = 0; n < PT; ++n){
      float4 xv = *reinterpret_cast<const float4*>(&xp[n][r]);
      acc[n] = fmaf(xv.x, w0, acc[n]);
      acc[n] = fmaf(xv.y, w1, acc[n]);
      acc[n] = fmaf(xv.z, w2, acc[n]);
      acc[n] = fmaf(xv.w, w3, acc[n]);
    }
  }
  #pragma unroll
  for (int n = 0; n < PT; ++n)
    if (n < rows) out[(size_t)(p0+n)*D + j] = lreluf(acc[n]);
}

// ---------------- edge remap + stable compaction ----------------
__global__ void k_efill(float* __restrict__ e, long long n2){
  long long stride = (long long)gridDim.x*blockDim.x;
  for (long long i = (long long)blockIdx.x*blockDim.x + threadIdx.x; i < n2; i += stride)
    e[i] = -1.0f;
}

__global__ __launch_bounds__(256) void k_ecount(const int* __restrict__ erow, const int* __restrict__ ecol,
    const int* __restrict__ nmap, int E, int* __restrict__ bcount){
  __shared__ int sc[256];
  const int tid = threadIdx.x;
  const int base = blockIdx.x*EBLK + tid*ECH;
  int cnt = 0;
  #pragma unroll
  for (int q = 0; q < ECH; ++q){
    int e = base + q;
    if (e < E){
      if (nmap[erow[e]] >= 0 && nmap[ecol[e]] >= 0) cnt++;
    }
  }
  sc[tid] = cnt; __syncthreads();
  for (int s = 128; s > 0; s >>= 1){
    if (tid < s) sc[tid] += sc[tid+s];
    __syncthreads();
  }
  if (tid == 0) bcount[blockIdx.x] = sc[0];
}

__global__ __launch_bounds__(1024) void k_escan(const int* __restrict__ bcount, int nblk, int* __restrict__ boff){
  __shared__ int sh[1024];
  const int tid = threadIdx.x;
  int carry = 0;
  for (int s = 0; s < nblk; s += 1024){
    int v = (s + tid < nblk) ? bcount[s+tid] : 0;
    sh[tid] = v; __syncthreads();
    for (int d = 1; d < 1024; d <<= 1){
      int t = (tid >= d) ? sh[tid-d] : 0;
      __syncthreads();
      sh[tid] += t;
      __syncthreads();
    }
    if (s + tid < nblk) boff[s+tid] = carry + sh[tid] - v;
    carry += sh[1023];
    __syncthreads();
  }
}

__global__ __launch_bounds__(256) void k_escatter(const int* __restrict__ erow, const int* __restrict__ ecol,
    const int* __restrict__ nmap, int E, const int* __restrict__ boff,
    float* __restrict__ outR, float* __restrict__ outC){
  __shared__ int sc[256];
  const int tid = threadIdx.x;
  const int base = blockIdx.x*EBLK + tid*ECH;
  int mr[ECH], mc[ECH];
  int cnt = 0;
  #pragma unroll
  for (int q = 0; q < ECH; ++q){
    int e = base + q;
    int a = -1, b = -1;
    if (e < E){ a = nmap[erow[e]]; b = nmap[ecol[e]]; }
    mr[q] = a; mc[q] = b;
    if (a >= 0 && b >= 0) cnt++;
  }
  sc[tid] = cnt; __syncthreads();
  int v = cnt;
  for (int d = 1; d < 256; d <<= 1){
    int t = (tid >= d) ? sc[tid-d] : 0;
    __syncthreads();
    sc[tid] += t;
    __syncthreads();
  }
  int pos = boff[blockIdx.x] + sc[tid] - v;   // exclusive prefix, stable in edge order
  #pragma unroll
  for (int q = 0; q < ECH; ++q){
    if (mr[q] >= 0 && mc[q] >= 0){
      outR[pos] = (float)mr[q];
      outC[pos] = (float)mc[q];
      pos++;
    }
  }
}

// ---------------- host ----------------
extern "C" void kernel_launch(void* const* d_in, const int* in_sizes, int n_in,
                              void* d_out, int out_size, void* d_ws, size_t ws_size,
                              hipStream_t stream)
{
  const float* x   = (const float*)d_in[0];
  const int*   ei  = (const int*)d_in[1];
  const float* wS1 = (const float*)d_in[2];
  const float* bS1 = (const float*)d_in[3];
  const float* wS2 = (const float*)d_in[4];
  const float* bS2 = (const float*)d_in[5];
  const float* wF1 = (const float*)d_in[6];
  const float* bF1 = (const float*)d_in[7];
  const float* wF2 = (const float*)d_in[8];
  const float* bF2 = (const float*)d_in[9];
  const float* wP  = (const float*)d_in[10];
  const float* bP  = (const float*)d_in[11];
  const float* alpha = (const float*)d_in[12];
  const float* beta  = (const float*)d_in[13];
  (void)n_in; (void)out_size; (void)ws_size;

  const int N = in_sizes[0] / D;
  const int E = in_sizes[1] / 2;
  int k = (int)(0.5 * (double)N); if (k < 1) k = 1;
  int SORTN = 1; while (SORTN < N) SORTN <<= 1;   // 262144 for N=200000
  const int nblk_e = (E + EBLK - 1) / EBLK;

  char* w = (char*)d_ws;
  size_t off = 0;
  auto alloc = [&](size_t bytes)->char*{
    char* p = w + off;
    off = (off + bytes + 255) & ~(size_t)255;
    return p;
  };
  double* scores = (double*)alloc((size_t)N*8);
  u64*    keys   = (u64*)   alloc((size_t)SORTN*8);
  int*    idxs   = (int*)   alloc((size_t)SORTN*4);
  int*    deg    = (int*)   alloc((size_t)N*4);
  int*    nmap   = (int*)   alloc((size_t)N*4);
  double* s1b    = (double*)alloc((size_t)D*8);
  double* scal   = (double*)alloc(4*8);
  u64*    sumsq  = (u64*)   alloc(8);
  int*    bcount = (int*)   alloc((size_t)nblk_e*4);
  int*    boff   = (int*)   alloc((size_t)nblk_e*4);

  float* outX  = (float*)d_out;
  float* outER = outX  + (size_t)k*D;
  float* outEC = outER + (size_t)E;
  float* outS  = outEC + (size_t)E;

  hipMemsetAsync(deg,   0,    (size_t)N*4, stream);
  hipMemsetAsync(sumsq, 0,    8,           stream);
  hipMemsetAsync(nmap,  0xFF, (size_t)N*4, stream);   // = -1

  k_degree<<<2048, 256, 0, stream>>>(ei, E, deg);
  k_degsq <<<1024, 256, 0, stream>>>(deg, N, sumsq);
  k_prep  <<<1,    D,   0, stream>>>(wS1, alpha, beta, sumsq, s1b, scal);
  k_scores<<<(N + NT - 1)/NT, 256, 0, stream>>>(x, deg, wS1,bS1,wS2,bS2,wF1,bF1,wF2,bF2,
                                                s1b, scal, scores, N);
  k_build_keys<<<SORTN/256, 256, 0, stream>>>(scores, N, SORTN, keys, idxs);
  k_bsort_local<<<SORTN/2048, 1024, 0, stream>>>(keys, idxs);
  for (int size = 4096; size <= SORTN; size <<= 1){
    for (int stride = size >> 1; stride >= 2048; stride >>= 1)
      k_bpass<<<SORTN/512, 256, 0, stream>>>(keys, idxs, size, stride);
    k_bmerge_local<<<SORTN/2048, 1024, 0, stream>>>(keys, idxs, size);
  }
  k_nodemap_set<<<(k+255)/256, 256, 0, stream>>>(idxs, k, nmap);
  k_topk_out  <<<(k+255)/256, 256, 0, stream>>>(scores, idxs, k, outS);
  k_xpool     <<<(k+PT-1)/PT, 256, 0, stream>>>(x, idxs, wP, bP, outX, k);
  k_efill     <<<2048, 256, 0, stream>>>(outER, (long long)2*E);
  k_ecount    <<<nblk_e, 256, 0, stream>>>(ei, ei+E, nmap, E, bcount);
  k_escan     <<<1, 1024, 0, stream>>>(bcount, nblk_e, boff);
  k_escatter  <<<nblk_e, 256, 0, stream>>>(ei, ei+E, nmap, E, boff, outER, outEC);
}

// Round 2
// 1710.147 us; speedup vs baseline: 2.0886x; 2.0886x over previous
//
#include <hip/hip_runtime.h>
#include <math.h>

typedef unsigned long long u64;

#define D   256
#define ECH 16          // edges per thread
#define EBLK (256*ECH)  // edges per block

__device__ __forceinline__ double lrelu(double v){ return v > 0.0 ? v : 0.2*v; }
__device__ __forceinline__ float  lreluf(float v){ return v > 0.0f ? v : 0.2f*v; }

// ---------------- degree ----------------
__global__ void k_degree(const int* __restrict__ row, int E, int* __restrict__ deg){
  int stride = gridDim.x*blockDim.x;
  for (int i = blockIdx.x*blockDim.x + threadIdx.x; i < E; i += stride)
    atomicAdd(&deg[row[i]], 1);
}

__global__ void k_degsq(const int* __restrict__ deg, int N, u64* __restrict__ out){
  __shared__ u64 sh[256];
  u64 local = 0;
  int stride = gridDim.x*blockDim.x;
  for (int i = blockIdx.x*blockDim.x + threadIdx.x; i < N; i += stride){
    u64 d = (u64)deg[i];
    local += d*d;
  }
  sh[threadIdx.x] = local; __syncthreads();
  for (int s = 128; s > 0; s >>= 1){
    if (threadIdx.x < s) sh[threadIdx.x] += sh[threadIdx.x+s];
    __syncthreads();
  }
  if (threadIdx.x == 0) atomicAdd(out, sh[0]);
}

// s1b[j] = sum_{r=256..511} w_s1[r][j]  (bottom-half column sums), plus scalar weights
__global__ void k_prep(const float* __restrict__ wS1, const float* __restrict__ alpha,
                       const float* __restrict__ beta, const u64* __restrict__ sumsq,
                       double* __restrict__ s1b, double* __restrict__ scal){
  int j = threadIdx.x;
  double s = 0.0;
  for (int r = 0; r < D; ++r) s += (double)wS1[(D + r)*D + j];
  s1b[j] = s;
  if (j == 0){
    double a = 1.0/(1.0 + exp(-(double)alpha[0]));
    double b = 1.0/(1.0 + exp(-(double)beta[0]));
    scal[0] = a/(a+b);
    scal[1] = b/(a+b);
    double dn = sqrt((double)(*sumsq));
    scal[2] = dn > 1e-12 ? dn : 1e-12;
  }
}

// ---------------- scores (f64, register-tiled GEMM) ----------------
// Fused GEMM: M=N(nodes) x N=384(cols: 0..255 -> W_s1 top, 256..383 -> W_f1) x K=256.
// Block: 256 thr, 32 nodes. Thread (a=tid>>6, cg=tid&63): 8 nodes x 6 cols (q*64+cg).
// x in LDS (f64, broadcast reads); w streamed from global (L2-resident), 1-deep prefetch.
__global__ __launch_bounds__(256, 3) void k_scores(
    const float* __restrict__ x,
    const int*   __restrict__ deg,
    const float* __restrict__ wS1, const float* __restrict__ bS1,
    const float* __restrict__ wS2, const float* __restrict__ bS2,
    const float* __restrict__ wF1, const float* __restrict__ bF1,
    const float* __restrict__ wF2, const float* __restrict__ bF2,
    const double* __restrict__ s1b, const double* __restrict__ scal,
    double* __restrict__ scores, int N)
{
  __shared__ double xs[128][32];   // 32 KiB, one K-chunk, layout [k][node]
  __shared__ double dn[32];

  const int tid = threadIdx.x;
  const int node0 = blockIdx.x * 32;
  const int a8 = (tid >> 6) * 8;   // first of this wave's 8 nodes
  const int cg = tid & 63;

  if (tid < 32){
    int node = node0 + tid;
    dn[tid] = (node < N) ? ((double)deg[node] / scal[2]) : 0.0;
  }

  double acc[8][6];
  #pragma unroll
  for (int n = 0; n < 8; ++n)
    #pragma unroll
    for (int q = 0; q < 6; ++q) acc[n][q] = 0.0;

  const float* pA = wS1 + cg;   // cols q*64+cg, q=0..3 ; row stride 256
  const float* pB = wF1 + cg;   // cols (q-4)*64+cg    ; row stride 128
  float w0 = pA[0], w1 = pA[64], w2 = pA[128], w3 = pA[192];
  float w4 = pB[0], w5 = pB[64];

  for (int c = 0; c < 2; ++c){
    // ---- stage chunk c: x[node][c*128 .. c*128+127] -> xs[k][node] (f64) ----
    {
      const int nloc = tid & 31, kseg = tid >> 5;   // 8 segs x 16 k
      const int node = node0 + nloc;
      const float* src = x + (size_t)node*D + c*128 + kseg*16;
      float4 f0, f1, f2, f3;
      if (node < N){
        f0 = *(const float4*)(src+0);  f1 = *(const float4*)(src+4);
        f2 = *(const float4*)(src+8);  f3 = *(const float4*)(src+12);
      } else {
        f0 = f1 = f2 = f3 = make_float4(0.f,0.f,0.f,0.f);
      }
      const int kb = kseg*16;
      xs[kb+ 0][nloc]=(double)f0.x; xs[kb+ 1][nloc]=(double)f0.y;
      xs[kb+ 2][nloc]=(double)f0.z; xs[kb+ 3][nloc]=(double)f0.w;
      xs[kb+ 4][nloc]=(double)f1.x; xs[kb+ 5][nloc]=(double)f1.y;
      xs[kb+ 6][nloc]=(double)f1.z; xs[kb+ 7][nloc]=(double)f1.w;
      xs[kb+ 8][nloc]=(double)f2.x; xs[kb+ 9][nloc]=(double)f2.y;
      xs[kb+10][nloc]=(double)f2.z; xs[kb+11][nloc]=(double)f2.w;
      xs[kb+12][nloc]=(double)f3.x; xs[kb+13][nloc]=(double)f3.y;
      xs[kb+14][nloc]=(double)f3.z; xs[kb+15][nloc]=(double)f3.w;
    }
    __syncthreads();

    for (int k = 0; k < 128; ++k){
      const int kg = c*128 + k;
      const float* qA = (kg < 255) ? pA + 256 : pA;   // prefetch next row (clamped)
      const float* qB = (kg < 255) ? pB + 128 : pB;
      float u0 = qA[0], u1 = qA[64], u2 = qA[128], u3 = qA[192];
      float u4 = qB[0], u5 = qB[64];

      double2 t0 = *(const double2*)&xs[k][a8+0];
      double2 t1 = *(const double2*)&xs[k][a8+2];
      double2 t2 = *(const double2*)&xs[k][a8+4];
      double2 t3 = *(const double2*)&xs[k][a8+6];
      double xv[8] = {t0.x, t0.y, t1.x, t1.y, t2.x, t2.y, t3.x, t3.y};

      const double d0 = (double)w0, d1 = (double)w1, d2 = (double)w2;
      const double d3 = (double)w3, d4 = (double)w4, d5 = (double)w5;
      #pragma unroll
      for (int n = 0; n < 8; ++n){
        acc[n][0] = fma(xv[n], d0, acc[n][0]);
        acc[n][1] = fma(xv[n], d1, acc[n][1]);
        acc[n][2] = fma(xv[n], d2, acc[n][2]);
        acc[n][3] = fma(xv[n], d3, acc[n][3]);
        acc[n][4] = fma(xv[n], d4, acc[n][4]);
        acc[n][5] = fma(xv[n], d5, acc[n][5]);
      }
      w0=u0; w1=u1; w2=u2; w3=u3; w4=u4; w5=u5;
      pA = qA; pB = qB;
    }
    __syncthreads();
  }

  // ---- epilogue: activation + score weights, in-wave reduction over 64 lanes ----
  const int lane = tid & 63;
  const double sb0 = s1b[cg], sb1 = s1b[cg+64], sb2 = s1b[cg+128], sb3 = s1b[cg+192];
  const double b0 = (double)bS1[cg],     b1 = (double)bS1[cg+64];
  const double b2 = (double)bS1[cg+128], b3 = (double)bS1[cg+192];
  const double v0 = (double)wS2[cg],     v1 = (double)wS2[cg+64];
  const double v2 = (double)wS2[cg+128], v3 = (double)wS2[cg+192];
  const double bf0 = (double)bF1[cg], bf1 = (double)bF1[cg+64];
  const double vf0 = (double)wF2[cg], vf1 = (double)wF2[cg+64];
  const double bs2 = (double)bS2[0], bff2 = (double)bF2[0];
  const double sc0 = scal[0], sc1 = scal[1];

  #pragma unroll
  for (int n = 0; n < 8; ++n){
    const double dnv = dn[a8+n];
    double sp = lrelu(acc[n][0] + fma(dnv, sb0, b0)) * v0
              + lrelu(acc[n][1] + fma(dnv, sb1, b1)) * v1
              + lrelu(acc[n][2] + fma(dnv, sb2, b2)) * v2
              + lrelu(acc[n][3] + fma(dnv, sb3, b3)) * v3;
    double fp = lrelu(acc[n][4] + bf0) * vf0
              + lrelu(acc[n][5] + bf1) * vf1;
    #pragma unroll
    for (int off = 32; off > 0; off >>= 1){
      sp += __shfl_down(sp, off);
      fp += __shfl_down(fp, off);
    }
    if (lane == 0){
      int node = node0 + a8 + n;
      if (node < N) scores[node] = sc0*(sp + bs2) + sc1*(fp + bff2);
    }
  }
}

// ---------------- top-k via bitonic sort (desc score, asc idx) ----------------
__global__ void k_build_keys(const double* __restrict__ scores, int N, int SORTN,
                             u64* __restrict__ keys, int* __restrict__ idxs){
  int i = blockIdx.x*blockDim.x + threadIdx.x;
  if (i >= SORTN) return;
  u64 kk;
  if (i < N){
    u64 u = (u64)__double_as_longlong(scores[i]);
    u = (u >> 63) ? ~u : (u | 0x8000000000000000ULL);  // ascending in score
    kk = ~u;                                           // ascending key = descending score
  } else {
    kk = 0xFFFFFFFFFFFFFFFFULL;                        // pad sorts last
  }
  keys[i] = kk;
  idxs[i] = i;
}

__device__ __forceinline__ bool kgreater(u64 ka, int ia, u64 kb, int ib){
  return (ka > kb) || (ka == kb && ia > ib);
}

// 4096 elements per block, 1024 threads, 2 pairs/thread/stage. LDS 48 KiB.
__global__ __launch_bounds__(1024) void k_bsort_local(u64* __restrict__ keys, int* __restrict__ idxs){
  __shared__ u64 sk[4096];
  __shared__ int si[4096];
  const int tid = threadIdx.x;
  const int base = blockIdx.x * 4096;
  #pragma unroll
  for (int e = 0; e < 4; ++e){
    sk[tid + e*1024] = keys[base + tid + e*1024];
    si[tid + e*1024] = idxs[base + tid + e*1024];
  }
  __syncthreads();
  for (int size = 2; size <= 4096; size <<= 1){
    for (int stride = size >> 1; stride > 0; stride >>= 1){
      #pragma unroll
      for (int pp = 0; pp < 2; ++pp){
        int p  = tid + pp*1024;
        int i  = 2*p - (p & (stride-1));
        int jj = i + stride;
        bool up = (((base + i) & size) == 0);
        u64 ki = sk[i], kj = sk[jj];
        int ii = si[i], ij = si[jj];
        if (kgreater(ki, ii, kj, ij) == up){
          sk[i] = kj; sk[jj] = ki; si[i] = ij; si[jj] = ii;
        }
      }
      __syncthreads();
    }
  }
  #pragma unroll
  for (int e = 0; e < 4; ++e){
    keys[base + tid + e*1024] = sk[tid + e*1024];
    idxs[base + tid + e*1024] = si[tid + e*1024];
  }
}

__global__ void k_bpass(u64* __restrict__ keys, int* __restrict__ idxs, int size, int stride){
  int t  = blockIdx.x*blockDim.x + threadIdx.x;
  int i  = 2*t - (t & (stride-1));
  int jj = i + stride;
  bool up = ((i & size) == 0);
  u64 ki = keys[i], kj = keys[jj];
  int ii = idxs[i], ij = idxs[jj];
  if (kgreater(ki, ii, kj, ij) == up){
    keys[i] = kj; keys[jj] = ki; idxs[i] = ij; idxs[jj] = ii;
  }
}

__global__ __launch_bounds__(1024) void k_bmerge_local(u64* __restrict__ keys, int* __restrict__ idxs, int size){
  __shared__ u64 sk[4096];
  __shared__ int si[4096];
  const int tid = threadIdx.x;
  const int base = blockIdx.x * 4096;
  #pragma unroll
  for (int e = 0; e < 4; ++e){
    sk[tid + e*1024] = keys[base + tid + e*1024];
    si[tid + e*1024] = idxs[base + tid + e*1024];
  }
  __syncthreads();
  for (int stride = 2048; stride > 0; stride >>= 1){
    #pragma unroll
    for (int pp = 0; pp < 2; ++pp){
      int p  = tid + pp*1024;
      int i  = 2*p - (p & (stride-1));
      int jj = i + stride;
      bool up = (((base + i) & size) == 0);
      u64 ki = sk[i], kj = sk[jj];
      int ii = si[i], ij = si[jj];
      if (kgreater(ki, ii, kj, ij) == up){
        sk[i] = kj; sk[jj] = ki; si[i] = ij; si[jj] = ii;
      }
    }
    __syncthreads();
  }
  #pragma unroll
  for (int e = 0; e < 4; ++e){
    keys[base + tid + e*1024] = sk[tid + e*1024];
    idxs[base + tid + e*1024] = si[tid + e*1024];
  }
}

// ---------------- post-topk outputs ----------------
__global__ void k_nodemap_set(const int* __restrict__ idxs, int k, int* __restrict__ nmap){
  int p = blockIdx.x*blockDim.x + threadIdx.x;
  if (p < k) nmap[idxs[p]] = p;
}

__global__ void k_topk_out(const double* __restrict__ scores, const int* __restrict__ idxs,
                           int k, float* __restrict__ outS){
  int p = blockIdx.x*blockDim.x + threadIdx.x;
  if (p < k) outS[p] = (float)scores[idxs[p]];
}

// register-tiled f32 GEMM: 32 rows/block, thread = 8 rows x 4 cols
__global__ __launch_bounds__(256) void k_xpool(const float* __restrict__ x, const int* __restrict__ idxs,
    const float* __restrict__ wP, const float* __restrict__ bP, float* __restrict__ out, int kk){
  __shared__ float xp[256][32];   // 32 KiB, [k][row]
  const int tid = threadIdx.x;
  const int p0 = blockIdx.x * 32;
  if (p0 >= kk) return;
  const int a8 = (tid >> 6) * 8;
  const int cg = tid & 63;

  {
    const int rl = tid & 31, kseg = tid >> 5;   // 8 segs x 32 k
    int p = p0 + rl; if (p >= kk) p = kk - 1;
    const float* src = x + (size_t)idxs[p]*D + kseg*32;
    #pragma unroll
    for (int i4 = 0; i4 < 8; ++i4){
      float4 f = *(const float4*)(src + i4*4);
      const int kb = kseg*32 + i4*4;
      xp[kb+0][rl] = f.x; xp[kb+1][rl] = f.y; xp[kb+2][rl] = f.z; xp[kb+3][rl] = f.w;
    }
  }
  __syncthreads();

  float acc[8][4];
  {
    const float bq0 = bP[cg], bq1 = bP[cg+64], bq2 = bP[cg+128], bq3 = bP[cg+192];
    #pragma unroll
    for (int n = 0; n < 8; ++n){ acc[n][0]=bq0; acc[n][1]=bq1; acc[n][2]=bq2; acc[n][3]=bq3; }
  }
  const float* pP = wP + cg;
  float w0 = pP[0], w1 = pP[64], w2 = pP[128], w3 = pP[192];
  for (int k = 0; k < 256; ++k){
    const float* qP = (k < 255) ? pP + 256 : pP;
    float u0 = qP[0], u1 = qP[64], u2 = qP[128], u3 = qP[192];
    float4 t0 = *(const float4*)&xp[k][a8+0];
    float4 t1 = *(const float4*)&xp[k][a8+4];
    float xv[8] = {t0.x, t0.y, t0.z, t0.w, t1.x, t1.y, t1.z, t1.w};
    #pragma unroll
    for (int n = 0; n < 8; ++n){
      acc[n][0] = fmaf(xv[n], w0, acc[n][0]);
      acc[n][1] = fmaf(xv[n], w1, acc[n][1]);
      acc[n][2] = fmaf(xv[n], w2, acc[n][2]);
      acc[n][3] = fmaf(xv[n], w3, acc[n][3]);
    }
    w0=u0; w1=u1; w2=u2; w3=u3; pP = qP;
  }
  #pragma unroll
  for (int n = 0; n < 8; ++n){
    int p = p0 + a8 + n;
    if (p < kk){
      float* o = out + (size_t)p*D + cg;
      o[0]   = lreluf(acc[n][0]);
      o[64]  = lreluf(acc[n][1]);
      o[128] = lreluf(acc[n][2]);
      o[192] = lreluf(acc[n][3]);
    }
  }
}

// ---------------- edge remap + stable compaction ----------------
__global__ void k_efill(float* __restrict__ e, long long n2){
  long long stride = (long long)gridDim.x*blockDim.x;
  for (long long i = (long long)blockIdx.x*blockDim.x + threadIdx.x; i < n2; i += stride)
    e[i] = -1.0f;
}

__global__ __launch_bounds__(256) void k_ecount(const int* __restrict__ erow, const int* __restrict__ ecol,
    const int* __restrict__ nmap, int E, int* __restrict__ bcount){
  __shared__ int sc[256];
  const int tid = threadIdx.x;
  const int base = blockIdx.x*EBLK + tid*ECH;
  int cnt = 0;
  #pragma unroll
  for (int q = 0; q < ECH; ++q){
    int e = base + q;
    if (e < E){
      if (nmap[erow[e]] >= 0 && nmap[ecol[e]] >= 0) cnt++;
    }
  }
  sc[tid] = cnt; __syncthreads();
  for (int s = 128; s > 0; s >>= 1){
    if (tid < s) sc[tid] += sc[tid+s];
    __syncthreads();
  }
  if (tid == 0) bcount[blockIdx.x] = sc[0];
}

__global__ __launch_bounds__(1024) void k_escan(const int* __restrict__ bcount, int nblk, int* __restrict__ boff){
  __shared__ int sh[1024];
  const int tid = threadIdx.x;
  int carry = 0;
  for (int s = 0; s < nblk; s += 1024){
    int v = (s + tid < nblk) ? bcount[s+tid] : 0;
    sh[tid] = v; __syncthreads();
    for (int d = 1; d < 1024; d <<= 1){
      int t = (tid >= d) ? sh[tid-d] : 0;
      __syncthreads();
      sh[tid] += t;
      __syncthreads();
    }
    if (s + tid < nblk) boff[s+tid] = carry + sh[tid] - v;
    carry += sh[1023];
    __syncthreads();
  }
}

__global__ __launch_bounds__(256) void k_escatter(const int* __restrict__ erow, const int* __restrict__ ecol,
    const int* __restrict__ nmap, int E, const int* __restrict__ boff,
    float* __restrict__ outR, float* __restrict__ outC){
  __shared__ int sc[256];
  const int tid = threadIdx.x;
  const int base = blockIdx.x*EBLK + tid*ECH;
  int mr[ECH], mc[ECH];
  int cnt = 0;
  #pragma unroll
  for (int q = 0; q < ECH; ++q){
    int e = base + q;
    int a = -1, b = -1;
    if (e < E){ a = nmap[erow[e]]; b = nmap[ecol[e]]; }
    mr[q] = a; mc[q] = b;
    if (a >= 0 && b >= 0) cnt++;
  }
  sc[tid] = cnt; __syncthreads();
  int v = cnt;
  for (int d = 1; d < 256; d <<= 1){
    int t = (tid >= d) ? sc[tid-d] : 0;
    __syncthreads();
    sc[tid] += t;
    __syncthreads();
  }
  int pos = boff[blockIdx.x] + sc[tid] - v;   // exclusive prefix, stable in edge order
  #pragma unroll
  for (int q = 0; q < ECH; ++q){
    if (mr[q] >= 0 && mc[q] >= 0){
      outR[pos] = (float)mr[q];
      outC[pos] = (float)mc[q];
      pos++;
    }
  }
}

// ---------------- host ----------------
extern "C" void kernel_launch(void* const* d_in, const int* in_sizes, int n_in,
                              void* d_out, int out_size, void* d_ws, size_t ws_size,
                              hipStream_t stream)
{
  const float* x   = (const float*)d_in[0];
  const int*   ei  = (const int*)d_in[1];
  const float* wS1 = (const float*)d_in[2];
  const float* bS1 = (const float*)d_in[3];
  const float* wS2 = (const float*)d_in[4];
  const float* bS2 = (const float*)d_in[5];
  const float* wF1 = (const float*)d_in[6];
  const float* bF1 = (const float*)d_in[7];
  const float* wF2 = (const float*)d_in[8];
  const float* bF2 = (const float*)d_in[9];
  const float* wP  = (const float*)d_in[10];
  const float* bP  = (const float*)d_in[11];
  const float* alpha = (const float*)d_in[12];
  const float* beta  = (const float*)d_in[13];
  (void)n_in; (void)out_size; (void)ws_size;

  const int N = in_sizes[0] / D;
  const int E = in_sizes[1] / 2;
  int k = (int)(0.5 * (double)N); if (k < 1) k = 1;
  int SORTN = 4096; while (SORTN < N) SORTN <<= 1;   // 262144 for N=200000
  const int nblk_e = (E + EBLK - 1) / EBLK;

  char* w = (char*)d_ws;
  size_t off = 0;
  auto alloc = [&](size_t bytes)->char*{
    char* p = w + off;
    off = (off + bytes + 255) & ~(size_t)255;
    return p;
  };
  double* scores = (double*)alloc((size_t)N*8);
  u64*    keys   = (u64*)   alloc((size_t)SORTN*8);
  int*    idxs   = (int*)   alloc((size_t)SORTN*4);
  int*    deg    = (int*)   alloc((size_t)N*4);
  int*    nmap   = (int*)   alloc((size_t)N*4);
  double* s1b    = (double*)alloc((size_t)D*8);
  double* scal   = (double*)alloc(4*8);
  u64*    sumsq  = (u64*)   alloc(8);
  int*    bcount = (int*)   alloc((size_t)nblk_e*4);
  int*    boff   = (int*)   alloc((size_t)nblk_e*4);

  float* outX  = (float*)d_out;
  float* outER = outX  + (size_t)k*D;
  float* outEC = outER + (size_t)E;
  float* outS  = outEC + (size_t)E;

  hipMemsetAsync(deg,   0,    (size_t)N*4, stream);
  hipMemsetAsync(sumsq, 0,    8,           stream);
  hipMemsetAsync(nmap,  0xFF, (size_t)N*4, stream);   // = -1

  k_degree<<<2048, 256, 0, stream>>>(ei, E, deg);
  k_degsq <<<1024, 256, 0, stream>>>(deg, N, sumsq);
  k_prep  <<<1,    D,   0, stream>>>(wS1, alpha, beta, sumsq, s1b, scal);
  k_scores<<<(N + 31)/32, 256, 0, stream>>>(x, deg, wS1,bS1,wS2,bS2,wF1,bF1,wF2,bF2,
                                            s1b, scal, scores, N);
  k_build_keys<<<SORTN/256, 256, 0, stream>>>(scores, N, SORTN, keys, idxs);
  k_bsort_local<<<SORTN/4096, 1024, 0, stream>>>(keys, idxs);
  for (int size = 8192; size <= SORTN; size <<= 1){
    for (int stride = size >> 1; stride >= 4096; stride >>= 1)
      k_bpass<<<SORTN/512, 256, 0, stream>>>(keys, idxs, size, stride);
    k_bmerge_local<<<SORTN/4096, 1024, 0, stream>>>(keys, idxs, size);
  }
  k_nodemap_set<<<(k+255)/256, 256, 0, stream>>>(idxs, k, nmap);
  k_topk_out  <<<(k+255)/256, 256, 0, stream>>>(scores, idxs, k, outS);
  k_xpool     <<<(k+31)/32, 256, 0, stream>>>(x, idxs, wP, bP, outX, k);
  k_efill     <<<2048, 256, 0, stream>>>(outER, (long long)2*E);
  k_ecount    <<<nblk_e, 256, 0, stream>>>(ei, ei+E, nmap, E, bcount);
  k_escan     <<<1, 1024, 0, stream>>>(bcount, nblk_e, boff);
  k_escatter  <<<nblk_e, 256, 0, stream>>>(ei, ei+E, nmap, E, boff, outER, outEC);
}

// Round 3
// 1457.760 us; speedup vs baseline: 2.4501x; 1.1731x over previous
//
#include <hip/hip_runtime.h>
#include <math.h>

typedef unsigned long long u64;
typedef unsigned int u32;

#define D   256
#define ECH 16          // edges per thread
#define EBLK (256*ECH)  // edges per block
#define BAND_W 4096     // rank window half-width around k for f64 refinement
#define BAND_DELTA 1e-3f

__device__ __forceinline__ double lrelu(double v){ return v > 0.0 ? v : 0.2*v; }
__device__ __forceinline__ float  lreluf(float v){ return v > 0.0f ? v : 0.2f*v; }

// ---------------- degree ----------------
__global__ void k_degree(const int* __restrict__ row, int E, int* __restrict__ deg){
  int stride = gridDim.x*blockDim.x;
  for (int i = blockIdx.x*blockDim.x + threadIdx.x; i < E; i += stride)
    atomicAdd(&deg[row[i]], 1);
}

__global__ void k_degsq(const int* __restrict__ deg, int N, u64* __restrict__ out){
  __shared__ u64 sh[256];
  u64 local = 0;
  int stride = gridDim.x*blockDim.x;
  for (int i = blockIdx.x*blockDim.x + threadIdx.x; i < N; i += stride){
    u64 d = (u64)deg[i];
    local += d*d;
  }
  sh[threadIdx.x] = local; __syncthreads();
  for (int s = 128; s > 0; s >>= 1){
    if (threadIdx.x < s) sh[threadIdx.x] += sh[threadIdx.x+s];
    __syncthreads();
  }
  if (threadIdx.x == 0) atomicAdd(out, sh[0]);
}

// s1b[j] = sum_{r=256..511} w_s1[r][j]; plus scalar weights (f64 + f32 copies)
__global__ void k_prep(const float* __restrict__ wS1, const float* __restrict__ alpha,
                       const float* __restrict__ beta, const u64* __restrict__ sumsq,
                       double* __restrict__ s1b, double* __restrict__ scal,
                       float* __restrict__ s1bf, float* __restrict__ scalf){
  int j = threadIdx.x;
  double s = 0.0;
  for (int r = 0; r < D; ++r) s += (double)wS1[(D + r)*D + j];
  s1b[j] = s;
  s1bf[j] = (float)s;
  if (j == 0){
    double a = 1.0/(1.0 + exp(-(double)alpha[0]));
    double b = 1.0/(1.0 + exp(-(double)beta[0]));
    scal[0] = a/(a+b);
    scal[1] = b/(a+b);
    double dn = sqrt((double)(*sumsq));
    scal[2] = dn > 1e-12 ? dn : 1e-12;
    scalf[0] = (float)scal[0];
    scalf[1] = (float)scal[1];
    scalf[2] = (float)(1.0/scal[2]);
  }
}

// ---------------- scores (f32, register-tiled GEMM) + packed sort keys ----------------
// 64 nodes/block, 256 thr. Thread (wave w=tid>>6, cg=tid&63): 16 nodes x 6 cols.
// cols 0..255 -> W_s1 top (q*64+cg, q=0..3); 256..383 -> W_f1 ((q-4)*64+cg).
__global__ __launch_bounds__(256) void k_scores32(
    const float* __restrict__ x,
    const int*   __restrict__ deg,
    const float* __restrict__ wS1, const float* __restrict__ bS1,
    const float* __restrict__ wS2, const float* __restrict__ bS2,
    const float* __restrict__ wF1, const float* __restrict__ bF1,
    const float* __restrict__ wF2, const float* __restrict__ bF2,
    const float* __restrict__ s1bf, const float* __restrict__ scalf,
    float* __restrict__ s32, u64* __restrict__ keys, int N, int SORTN)
{
  __shared__ float xs[128][64];   // 32 KiB, one K-chunk, layout [k][node]
  __shared__ float dn[64];

  const int tid = threadIdx.x;
  const int node0 = blockIdx.x * 64;

  if (node0 >= N){                 // pure-pad block
    if (tid < 64){
      int i = node0 + tid;
      if (i < SORTN) keys[i] = ~0ULL;
    }
    return;
  }

  const int a16 = (tid >> 6) * 16;  // first of this wave's 16 nodes
  const int cg = tid & 63;

  if (tid < 64){
    int node = node0 + tid;
    dn[tid] = (node < N) ? ((float)deg[node] * scalf[2]) : 0.0f;
  }

  float acc[16][6];
  #pragma unroll
  for (int n = 0; n < 16; ++n)
    #pragma unroll
    for (int q = 0; q < 6; ++q) acc[n][q] = 0.0f;

  const float* pA = wS1 + cg;   // row stride 256
  const float* pB = wF1 + cg;   // row stride 128
  float w0 = pA[0], w1 = pA[64], w2 = pA[128], w3 = pA[192];
  float w4 = pB[0], w5 = pB[64];

  for (int c = 0; c < 2; ++c){
    // stage chunk c: x[node][c*128 .. +127] -> xs[k][node]
    {
      const int nloc = tid & 63, kseg = tid >> 6;   // 4 segs x 32 k
      const int node = node0 + nloc;
      const float* src = x + (size_t)node*D + c*128 + kseg*32;
      #pragma unroll
      for (int i4 = 0; i4 < 8; ++i4){
        float4 f = (node < N) ? *(const float4*)(src + i4*4) : make_float4(0.f,0.f,0.f,0.f);
        const int kb = kseg*32 + i4*4;
        xs[kb+0][nloc]=f.x; xs[kb+1][nloc]=f.y; xs[kb+2][nloc]=f.z; xs[kb+3][nloc]=f.w;
      }
    }
    __syncthreads();

    for (int kk2 = 0; kk2 < 128; ++kk2){
      const int kg = c*128 + kk2;
      const float* qA = (kg < 255) ? pA + 256 : pA;
      const float* qB = (kg < 255) ? pB + 128 : pB;
      float u0 = qA[0], u1 = qA[64], u2 = qA[128], u3 = qA[192];
      float u4 = qB[0], u5 = qB[64];

      float4 t0 = *(const float4*)&xs[kk2][a16+0];
      float4 t1 = *(const float4*)&xs[kk2][a16+4];
      float4 t2 = *(const float4*)&xs[kk2][a16+8];
      float4 t3 = *(const float4*)&xs[kk2][a16+12];
      float xv[16] = {t0.x,t0.y,t0.z,t0.w, t1.x,t1.y,t1.z,t1.w,
                      t2.x,t2.y,t2.z,t2.w, t3.x,t3.y,t3.z,t3.w};
      #pragma unroll
      for (int n = 0; n < 16; ++n){
        acc[n][0] = fmaf(xv[n], w0, acc[n][0]);
        acc[n][1] = fmaf(xv[n], w1, acc[n][1]);
        acc[n][2] = fmaf(xv[n], w2, acc[n][2]);
        acc[n][3] = fmaf(xv[n], w3, acc[n][3]);
        acc[n][4] = fmaf(xv[n], w4, acc[n][4]);
        acc[n][5] = fmaf(xv[n], w5, acc[n][5]);
      }
      w0=u0; w1=u1; w2=u2; w3=u3; w4=u4; w5=u5;
      pA = qA; pB = qB;
    }
    __syncthreads();
  }

  // epilogue: activation + score mix, in-wave 64-lane reduction
  const int lane = tid & 63;
  const float sb0 = s1bf[cg], sb1 = s1bf[cg+64], sb2 = s1bf[cg+128], sb3 = s1bf[cg+192];
  const float b0 = bS1[cg],     b1 = bS1[cg+64];
  const float b2 = bS1[cg+128], b3 = bS1[cg+192];
  const float v0 = wS2[cg],     v1 = wS2[cg+64];
  const float v2 = wS2[cg+128], v3 = wS2[cg+192];
  const float bf0 = bF1[cg], bf1 = bF1[cg+64];
  const float vf0 = wF2[cg], vf1 = wF2[cg+64];
  const float bs2 = bS2[0], bff2 = bF2[0];
  const float sc0 = scalf[0], sc1 = scalf[1];

  #pragma unroll
  for (int n = 0; n < 16; ++n){
    const float dnv = dn[a16+n];
    float sp = lreluf(acc[n][0] + fmaf(dnv, sb0, b0)) * v0
             + lreluf(acc[n][1] + fmaf(dnv, sb1, b1)) * v1
             + lreluf(acc[n][2] + fmaf(dnv, sb2, b2)) * v2
             + lreluf(acc[n][3] + fmaf(dnv, sb3, b3)) * v3;
    float fp = lreluf(acc[n][4] + bf0) * vf0
             + lreluf(acc[n][5] + bf1) * vf1;
    #pragma unroll
    for (int off = 32; off > 0; off >>= 1){
      sp += __shfl_down(sp, off);
      fp += __shfl_down(fp, off);
    }
    if (lane == 0){
      int node = node0 + a16 + n;
      if (node < N){
        float s = sc0*(sp + bs2) + sc1*(fp + bff2);
        s32[node] = s;
        u32 bits = __float_as_uint(s);
        u32 ord = (bits >> 31) ? ~bits : (bits | 0x80000000u);
        u32 key32 = ~ord;                     // ascending key = descending score
        keys[node] = ((u64)key32 << 32) | (u32)node;
      }
    }
  }
  if (tid < 64){                               // partial-block pad slots
    int i = node0 + tid;
    if (i >= N && i < SORTN) keys[i] = ~0ULL;
  }
}

// ---------------- bitonic sort on packed u64 (plain ascending compare) ----------------
// 8192 elements/block, 1024 threads, 4 pairs/thread/stage. LDS 64 KiB.
__global__ __launch_bounds__(1024) void k_bsort_local8k(u64* __restrict__ keys){
  __shared__ u64 sk[8192];
  const int tid = threadIdx.x;
  const int base = blockIdx.x * 8192;
  #pragma unroll
  for (int e = 0; e < 8; ++e) sk[tid + e*1024] = keys[base + tid + e*1024];
  __syncthreads();
  for (int size = 2; size <= 8192; size <<= 1){
    for (int stride = size >> 1; stride > 0; stride >>= 1){
      #pragma unroll
      for (int pp = 0; pp < 4; ++pp){
        int p  = tid + pp*1024;
        int i  = 2*p - (p & (stride-1));
        int jj = i + stride;
        bool up = (((base + i) & size) == 0);
        u64 ki = sk[i], kj = sk[jj];
        if ((ki > kj) == up){ sk[i] = kj; sk[jj] = ki; }
      }
      __syncthreads();
    }
  }
  #pragma unroll
  for (int e = 0; e < 8; ++e) keys[base + tid + e*1024] = sk[tid + e*1024];
}

__global__ __launch_bounds__(1024) void k_bmerge_local8k(u64* __restrict__ keys, int size){
  __shared__ u64 sk[8192];
  const int tid = threadIdx.x;
  const int base = blockIdx.x * 8192;
  #pragma unroll
  for (int e = 0; e < 8; ++e) sk[tid + e*1024] = keys[base + tid + e*1024];
  __syncthreads();
  for (int stride = 4096; stride > 0; stride >>= 1){
    #pragma unroll
    for (int pp = 0; pp < 4; ++pp){
      int p  = tid + pp*1024;
      int i  = 2*p - (p & (stride-1));
      int jj = i + stride;
      bool up = (((base + i) & size) == 0);
      u64 ki = sk[i], kj = sk[jj];
      if ((ki > kj) == up){ sk[i] = kj; sk[jj] = ki; }
    }
    __syncthreads();
  }
  #pragma unroll
  for (int e = 0; e < 8; ++e) keys[base + tid + e*1024] = sk[tid + e*1024];
}

__global__ void k_bpass(u64* __restrict__ keys, int size, int stride){
  int t  = blockIdx.x*blockDim.x + threadIdx.x;
  int i  = 2*t - (t & (stride-1));
  int jj = i + stride;
  bool up = ((i & size) == 0);
  u64 ki = keys[i], kj = keys[jj];
  if ((ki > kj) == up){ keys[i] = kj; keys[jj] = ki; }
}

// two strides (stride, stride/2) per launch; requires stride/2 >= local tile (8192)
__global__ void k_bpass2(u64* __restrict__ keys, int size, int stride){
  int t = blockIdx.x*blockDim.x + threadIdx.x;   // t < SORTN/4
  int h = stride >> 1;
  int q = t / h;
  int r = t & (h - 1);
  int i0 = q*(h<<2) + r;
  bool up = ((i0 & size) == 0);
  u64 k0 = keys[i0], k1 = keys[i0+h], k2 = keys[i0+2*h], k3 = keys[i0+3*h];
  u64 tswp;
  if ((k0 > k2) == up){ tswp=k0; k0=k2; k2=tswp; }   // stride pairs
  if ((k1 > k3) == up){ tswp=k1; k1=k3; k3=tswp; }
  if ((k0 > k1) == up){ tswp=k0; k0=k1; k1=tswp; }   // stride/2 pairs
  if ((k2 > k3) == up){ tswp=k2; k2=k3; k3=tswp; }
  keys[i0] = k0; keys[i0+h] = k1; keys[i0+2*h] = k2; keys[i0+3*h] = k3;
}

// ---------------- f64 band refinement around rank-k cutoff ----------------
__global__ void kr_cut(const u64* __restrict__ keys, int k, float* __restrict__ cutbuf,
                       int* __restrict__ r01){
  if (threadIdx.x == 0 && blockIdx.x == 0){
    u32 key32 = (u32)(keys[k-1] >> 32);
    u32 ord = ~key32;
    u32 u = (ord & 0x80000000u) ? (ord ^ 0x80000000u) : ~ord;
    float c = __uint_as_float(u);
    cutbuf[0] = c - BAND_DELTA;
    cutbuf[1] = c + BAND_DELTA;
    r01[0] = 0x7FFFFFFF;
    r01[1] = -1;
  }
}

// one block per rank in [k-W, k+W); rescore in f64 if f32 score within band
__global__ __launch_bounds__(256) void kr_rescore(
    const u64* __restrict__ keys, const float* __restrict__ s32,
    const float* __restrict__ x, const int* __restrict__ deg,
    const float* __restrict__ wS1, const float* __restrict__ bS1,
    const float* __restrict__ wS2, const float* __restrict__ bS2,
    const float* __restrict__ wF1, const float* __restrict__ bF1,
    const float* __restrict__ wF2, const float* __restrict__ bF2,
    const double* __restrict__ s1b, const double* __restrict__ scal,
    const float* __restrict__ cutbuf, int* __restrict__ r01,
    double* __restrict__ bandS, int k, int N)
{
  const int r = k - BAND_W + blockIdx.x;
  if (r < 0 || r >= N) return;
  const int node = (int)(u32)(keys[r] & 0xFFFFFFFFULL);
  const float s = s32[node];
  if (s < cutbuf[0] || s > cutbuf[1]) return;

  const int tid = threadIdx.x;
  if (tid == 0){ atomicMin(&r01[0], r); atomicMax(&r01[1], r); }

  __shared__ float xr[256];
  __shared__ double rsp[4], rfp[4];
  xr[tid] = x[(size_t)node*D + tid];
  __syncthreads();

  const int j = tid;
  double accA = (double)bS1[j] + ((double)deg[node]/scal[2]) * s1b[j];
  double accB = (j < 128) ? (double)bF1[j] : 0.0;
  for (int rr = 0; rr < D; ++rr){
    double xv = (double)xr[rr];
    accA = fma(xv, (double)wS1[rr*D + j], accA);
    if (j < 128) accB = fma(xv, (double)wF1[rr*128 + j], accB);
  }
  double sp = lrelu(accA) * (double)wS2[j];
  double fp = (j < 128) ? lrelu(accB) * (double)wF2[j] : 0.0;

  const int lane = tid & 63, wave = tid >> 6;
  #pragma unroll
  for (int off = 32; off > 0; off >>= 1){
    sp += __shfl_down(sp, off);
    fp += __shfl_down(fp, off);
  }
  if (lane == 0){ rsp[wave] = sp; rfp[wave] = fp; }
  __syncthreads();
  if (tid == 0){
    double SP = rsp[0]+rsp[1]+rsp[2]+rsp[3];
    double FP = rfp[0]+rfp[1]+rfp[2]+rfp[3];
    bandS[blockIdx.x] = scal[0]*(SP + (double)bS2[0]) + scal[1]*(FP + (double)bF2[0]);
  }
}

// re-sort the contiguous band segment [r0, r1] by (f64 score desc, idx asc)
__global__ __launch_bounds__(1024) void kr_bandsort(u64* __restrict__ keys,
    const double* __restrict__ bandS, const int* __restrict__ r01, int k){
  __shared__ double bs[8192];
  __shared__ int bi[8192];
  const int r0 = r01[0], r1 = r01[1];
  int nb = r1 - r0 + 1;
  if (nb <= 1) return;
  if (nb > 8192) nb = 8192;
  int M = 1; while (M < nb) M <<= 1;
  const int tid = threadIdx.x;
  const int sbase = r0 - (k - BAND_W);   // bandS slot of rank r0
  for (int m = tid; m < M; m += 1024){
    if (m < nb){ bs[m] = bandS[sbase + m]; bi[m] = (int)(u32)(keys[r0+m] & 0xFFFFFFFFULL); }
    else       { bs[m] = -1.0/0.0;         bi[m] = 0x7FFFFFFF; }
  }
  __syncthreads();
  for (int size = 2; size <= M; size <<= 1){
    for (int stride = size >> 1; stride > 0; stride >>= 1){
      for (int p = tid; p < (M >> 1); p += 1024){
        int i = 2*p - (p & (stride-1));
        int jj = i + stride;
        bool up = ((i & size) == 0);
        double si_ = bs[i], sj = bs[jj];
        int ii = bi[i], ij = bi[jj];
        bool gt = (si_ < sj) || (si_ == sj && ii > ij);  // "comes later" in desc/asc order
        if (gt == up){ bs[i]=sj; bs[jj]=si_; bi[i]=ij; bi[jj]=ii; }
      }
      __syncthreads();
    }
  }
  for (int m = tid; m < nb; m += 1024)
    keys[r0+m] = (u64)(u32)bi[m];
}

// ---------------- post-topk: node_map + topk_scores fused ----------------
__global__ void k_finalize(const u64* __restrict__ keys, const float* __restrict__ s32,
                           int k, int* __restrict__ nmap, float* __restrict__ outS){
  int p = blockIdx.x*blockDim.x + threadIdx.x;
  if (p < k){
    int node = (int)(u32)(keys[p] & 0xFFFFFFFFULL);
    nmap[node] = p;
    outS[p] = s32[node];
  }
}

// register-tiled f32 GEMM: 64 rows/block, thread = 16 rows x 4 cols
__global__ __launch_bounds__(256) void k_xpool(const float* __restrict__ x, const u64* __restrict__ keys,
    const float* __restrict__ wP, const float* __restrict__ bP, float* __restrict__ out, int kk){
  __shared__ float xp[256][64];   // 64 KiB, [k][row]
  const int tid = threadIdx.x;
  const int p0 = blockIdx.x * 64;
  if (p0 >= kk) return;
  const int a16 = (tid >> 6) * 16;
  const int cg = tid & 63;

  {
    const int rl = tid & 63, kseg = tid >> 6;   // 4 segs x 64 k
    int p = p0 + rl; if (p >= kk) p = kk - 1;
    int node = (int)(u32)(keys[p] & 0xFFFFFFFFULL);
    const float* src = x + (size_t)node*D + kseg*64;
    #pragma unroll
    for (int i4 = 0; i4 < 16; ++i4){
      float4 f = *(const float4*)(src + i4*4);
      const int kb = kseg*64 + i4*4;
      xp[kb+0][rl] = f.x; xp[kb+1][rl] = f.y; xp[kb+2][rl] = f.z; xp[kb+3][rl] = f.w;
    }
  }
  __syncthreads();

  float acc[16][4];
  {
    const float bq0 = bP[cg], bq1 = bP[cg+64], bq2 = bP[cg+128], bq3 = bP[cg+192];
    #pragma unroll
    for (int n = 0; n < 16; ++n){ acc[n][0]=bq0; acc[n][1]=bq1; acc[n][2]=bq2; acc[n][3]=bq3; }
  }
  const float* pP = wP + cg;
  float w0 = pP[0], w1 = pP[64], w2 = pP[128], w3 = pP[192];
  for (int kk2 = 0; kk2 < 256; ++kk2){
    const float* qP = (kk2 < 255) ? pP + 256 : pP;
    float u0 = qP[0], u1 = qP[64], u2 = qP[128], u3 = qP[192];
    float4 t0 = *(const float4*)&xp[kk2][a16+0];
    float4 t1 = *(const float4*)&xp[kk2][a16+4];
    float4 t2 = *(const float4*)&xp[kk2][a16+8];
    float4 t3 = *(const float4*)&xp[kk2][a16+12];
    float xv[16] = {t0.x,t0.y,t0.z,t0.w, t1.x,t1.y,t1.z,t1.w,
                    t2.x,t2.y,t2.z,t2.w, t3.x,t3.y,t3.z,t3.w};
    #pragma unroll
    for (int n = 0; n < 16; ++n){
      acc[n][0] = fmaf(xv[n], w0, acc[n][0]);
      acc[n][1] = fmaf(xv[n], w1, acc[n][1]);
      acc[n][2] = fmaf(xv[n], w2, acc[n][2]);
      acc[n][3] = fmaf(xv[n], w3, acc[n][3]);
    }
    w0=u0; w1=u1; w2=u2; w3=u3; pP = qP;
  }
  #pragma unroll
  for (int n = 0; n < 16; ++n){
    int p = p0 + a16 + n;
    if (p < kk){
      float* o = out + (size_t)p*D + cg;
      o[0]   = lreluf(acc[n][0]);
      o[64]  = lreluf(acc[n][1]);
      o[128] = lreluf(acc[n][2]);
      o[192] = lreluf(acc[n][3]);
    }
  }
}

// ---------------- edge remap + stable compaction ----------------
__global__ void k_efill(float* __restrict__ e, long long n2){
  long long stride = (long long)gridDim.x*blockDim.x;
  for (long long i = (long long)blockIdx.x*blockDim.x + threadIdx.x; i < n2; i += stride)
    e[i] = -1.0f;
}

__global__ __launch_bounds__(256) void k_ecount(const int* __restrict__ erow, const int* __restrict__ ecol,
    const int* __restrict__ nmap, int E, int* __restrict__ bcount){
  __shared__ int sc[256];
  const int tid = threadIdx.x;
  const int base = blockIdx.x*EBLK + tid*ECH;
  int cnt = 0;
  #pragma unroll
  for (int q = 0; q < ECH; ++q){
    int e = base + q;
    if (e < E){
      if (nmap[erow[e]] >= 0 && nmap[ecol[e]] >= 0) cnt++;
    }
  }
  sc[tid] = cnt; __syncthreads();
  for (int s = 128; s > 0; s >>= 1){
    if (tid < s) sc[tid] += sc[tid+s];
    __syncthreads();
  }
  if (tid == 0) bcount[blockIdx.x] = sc[0];
}

__global__ __launch_bounds__(1024) void k_escan(const int* __restrict__ bcount, int nblk, int* __restrict__ boff){
  __shared__ int sh[1024];
  const int tid = threadIdx.x;
  int carry = 0;
  for (int s = 0; s < nblk; s += 1024){
    int v = (s + tid < nblk) ? bcount[s+tid] : 0;
    sh[tid] = v; __syncthreads();
    for (int d = 1; d < 1024; d <<= 1){
      int t = (tid >= d) ? sh[tid-d] : 0;
      __syncthreads();
      sh[tid] += t;
      __syncthreads();
    }
    if (s + tid < nblk) boff[s+tid] = carry + sh[tid] - v;
    carry += sh[1023];
    __syncthreads();
  }
}

__global__ __launch_bounds__(256) void k_escatter(const int* __restrict__ erow, const int* __restrict__ ecol,
    const int* __restrict__ nmap, int E, const int* __restrict__ boff,
    float* __restrict__ outR, float* __restrict__ outC){
  __shared__ int sc[256];
  const int tid = threadIdx.x;
  const int base = blockIdx.x*EBLK + tid*ECH;
  int mr[ECH], mc[ECH];
  int cnt = 0;
  #pragma unroll
  for (int q = 0; q < ECH; ++q){
    int e = base + q;
    int a = -1, b = -1;
    if (e < E){ a = nmap[erow[e]]; b = nmap[ecol[e]]; }
    mr[q] = a; mc[q] = b;
    if (a >= 0 && b >= 0) cnt++;
  }
  sc[tid] = cnt; __syncthreads();
  int v = cnt;
  for (int d = 1; d < 256; d <<= 1){
    int t = (tid >= d) ? sc[tid-d] : 0;
    __syncthreads();
    sc[tid] += t;
    __syncthreads();
  }
  int pos = boff[blockIdx.x] + sc[tid] - v;   // exclusive prefix, stable in edge order
  #pragma unroll
  for (int q = 0; q < ECH; ++q){
    if (mr[q] >= 0 && mc[q] >= 0){
      outR[pos] = (float)mr[q];
      outC[pos] = (float)mc[q];
      pos++;
    }
  }
}

// ---------------- host ----------------
extern "C" void kernel_launch(void* const* d_in, const int* in_sizes, int n_in,
                              void* d_out, int out_size, void* d_ws, size_t ws_size,
                              hipStream_t stream)
{
  const float* x   = (const float*)d_in[0];
  const int*   ei  = (const int*)d_in[1];
  const float* wS1 = (const float*)d_in[2];
  const float* bS1 = (const float*)d_in[3];
  const float* wS2 = (const float*)d_in[4];
  const float* bS2 = (const float*)d_in[5];
  const float* wF1 = (const float*)d_in[6];
  const float* bF1 = (const float*)d_in[7];
  const float* wF2 = (const float*)d_in[8];
  const float* bF2 = (const float*)d_in[9];
  const float* wP  = (const float*)d_in[10];
  const float* bP  = (const float*)d_in[11];
  const float* alpha = (const float*)d_in[12];
  const float* beta  = (const float*)d_in[13];
  (void)n_in; (void)out_size; (void)ws_size;

  const int N = in_sizes[0] / D;
  const int E = in_sizes[1] / 2;
  int k = (int)(0.5 * (double)N); if (k < 1) k = 1;
  int SORTN = 8192; while (SORTN < N) SORTN <<= 1;   // 262144 for N=200000
  const int nblk_e = (E + EBLK - 1) / EBLK;

  char* w = (char*)d_ws;
  size_t off = 0;
  auto alloc = [&](size_t bytes)->char*{
    char* p = w + off;
    off = (off + bytes + 255) & ~(size_t)255;
    return p;
  };
  float*  s32    = (float*) alloc((size_t)N*4);
  u64*    keys   = (u64*)   alloc((size_t)SORTN*8);
  int*    deg    = (int*)   alloc((size_t)N*4);
  int*    nmap   = (int*)   alloc((size_t)N*4);
  double* s1b    = (double*)alloc((size_t)D*8);
  float*  s1bf   = (float*) alloc((size_t)D*4);
  double* scal   = (double*)alloc(4*8);
  float*  scalf  = (float*) alloc(4*4);
  u64*    sumsq  = (u64*)   alloc(8);
  float*  cutbuf = (float*) alloc(2*4);
  int*    r01    = (int*)   alloc(2*4);
  double* bandS  = (double*)alloc((size_t)2*BAND_W*8);
  int*    bcount = (int*)   alloc((size_t)nblk_e*4);
  int*    boff   = (int*)   alloc((size_t)nblk_e*4);

  float* outX  = (float*)d_out;
  float* outER = outX  + (size_t)k*D;
  float* outEC = outER + (size_t)E;
  float* outS  = outEC + (size_t)E;

  hipMemsetAsync(deg,   0,    (size_t)N*4, stream);
  hipMemsetAsync(sumsq, 0,    8,           stream);
  hipMemsetAsync(nmap,  0xFF, (size_t)N*4, stream);   // = -1

  k_degree<<<2048, 256, 0, stream>>>(ei, E, deg);
  k_degsq <<<1024, 256, 0, stream>>>(deg, N, sumsq);
  k_prep  <<<1,    D,   0, stream>>>(wS1, alpha, beta, sumsq, s1b, scal, s1bf, scalf);
  k_scores32<<<SORTN/64, 256, 0, stream>>>(x, deg, wS1,bS1,wS2,bS2,wF1,bF1,wF2,bF2,
                                           s1bf, scalf, s32, keys, N, SORTN);
  // sort packed keys ascending (= score desc, idx asc)
  k_bsort_local8k<<<SORTN/8192, 1024, 0, stream>>>(keys);
  for (int size = 16384; size <= SORTN; size <<= 1){
    int stride = size >> 1;
    while (stride >= 8192){
      if (stride >= 16384){
        k_bpass2<<<SORTN/4/256, 256, 0, stream>>>(keys, size, stride);
        stride >>= 2;
      } else {
        k_bpass<<<SORTN/2/256, 256, 0, stream>>>(keys, size, stride);
        stride >>= 1;
      }
    }
    k_bmerge_local8k<<<SORTN/8192, 1024, 0, stream>>>(keys, size);
  }
  // f64 band refinement around the cutoff
  kr_cut     <<<1, 64, 0, stream>>>(keys, k, cutbuf, r01);
  kr_rescore <<<2*BAND_W, 256, 0, stream>>>(keys, s32, x, deg, wS1,bS1,wS2,bS2,
                                            wF1,bF1,wF2,bF2, s1b, scal,
                                            cutbuf, r01, bandS, k, N);
  kr_bandsort<<<1, 1024, 0, stream>>>(keys, bandS, r01, k);

  k_finalize<<<(k+255)/256, 256, 0, stream>>>(keys, s32, k, nmap, outS);
  k_xpool   <<<(k+63)/64, 256, 0, stream>>>(x, keys, wP, bP, outX, k);
  k_efill   <<<2048, 256, 0, stream>>>(outER, (long long)2*E);
  k_ecount  <<<nblk_e, 256, 0, stream>>>(ei, ei+E, nmap, E, bcount);
  k_escan   <<<1, 1024, 0, stream>>>(bcount, nblk_e, boff);
  k_escatter<<<nblk_e, 256, 0, stream>>>(ei, ei+E, nmap, E, boff, outER, outEC);
}

// Round 4
// 1119.854 us; speedup vs baseline: 3.1895x; 1.3017x over previous
//
#include <hip/hip_runtime.h>
#include <math.h>

typedef unsigned long long u64;
typedef unsigned int u32;
typedef unsigned short u16;
typedef __attribute__((ext_vector_type(8))) short bf16x8;
typedef __attribute__((ext_vector_type(4))) float f32x4;

#define D   256
#define ECH 16          // edges per thread
#define EBLK (256*ECH)  // edges per block
#define BAND_W 4096     // rank window half-width around k for f64 refinement
#define BAND_DELTA 1e-3f

__device__ __forceinline__ double lrelu(double v){ return v > 0.0 ? v : 0.2*v; }
__device__ __forceinline__ float  lreluf(float v){ return v > 0.0f ? v : 0.2f*v; }

__device__ __forceinline__ u16 f2bf(float f){
  union{float f; u32 u;} v; v.f = f;
  u32 r = v.u + 0x7FFFu + ((v.u >> 16) & 1u);   // RNE
  return (u16)(r >> 16);
}
__device__ __forceinline__ float bf2f(u16 b){
  union{u32 u; float f;} v; v.u = ((u32)b) << 16; return v.f;
}

// ---------------- degree ----------------
__global__ void k_degree(const int* __restrict__ row, int E, int* __restrict__ deg){
  int stride = gridDim.x*blockDim.x;
  for (int i = blockIdx.x*blockDim.x + threadIdx.x; i < E; i += stride)
    atomicAdd(&deg[row[i]], 1);
}

__global__ void k_degsq(const int* __restrict__ deg, int N, u64* __restrict__ out){
  __shared__ u64 sh[256];
  u64 local = 0;
  int stride = gridDim.x*blockDim.x;
  for (int i = blockIdx.x*blockDim.x + threadIdx.x; i < N; i += stride){
    u64 d = (u64)deg[i];
    local += d*d;
  }
  sh[threadIdx.x] = local; __syncthreads();
  for (int s = 128; s > 0; s >>= 1){
    if (threadIdx.x < s) sh[threadIdx.x] += sh[threadIdx.x+s];
    __syncthreads();
  }
  if (threadIdx.x == 0) atomicAdd(out, sh[0]);
}

// s1b[j] = sum_{r=256..511} w_s1[r][j]; plus scalar weights (f64 + f32 copies)
__global__ void k_prep(const float* __restrict__ wS1, const float* __restrict__ alpha,
                       const float* __restrict__ beta, const u64* __restrict__ sumsq,
                       double* __restrict__ s1b, double* __restrict__ scal,
                       float* __restrict__ s1bf, float* __restrict__ scalf){
  int j = threadIdx.x;
  double s = 0.0;
  for (int r = 0; r < D; ++r) s += (double)wS1[(D + r)*D + j];
  s1b[j] = s;
  s1bf[j] = (float)s;
  if (j == 0){
    double a = 1.0/(1.0 + exp(-(double)alpha[0]));
    double b = 1.0/(1.0 + exp(-(double)beta[0]));
    scal[0] = a/(a+b);
    scal[1] = b/(a+b);
    double dn = sqrt((double)(*sumsq));
    scal[2] = dn > 1e-12 ? dn : 1e-12;
    scalf[0] = (float)scal[0];
    scalf[1] = (float)scal[1];
    scalf[2] = (float)(1.0/scal[2]);
  }
}

// ---------------- weight pre-swizzle into MFMA B-fragment order (hi/lo bf16) ---------
// wsw[((t*8 + sg)*64 + lane)*8 + i] = w[k][col], k = sg*32 + (lane>>4)*8 + i,
// col = t<16 ? t*16+(lane&15) (wS1 top)  :  (t-16)*16+(lane&15) (wF1)
__global__ void k_wsw(const float* __restrict__ wS1, const float* __restrict__ wF1,
                      u16* __restrict__ wswH, u16* __restrict__ wswL){
  int idx = blockIdx.x*blockDim.x + threadIdx.x;   // 24*8*64*8 = 98304
  int i    = idx & 7;
  int lane = (idx >> 3) & 63;
  int sg   = (idx >> 9) & 7;
  int t    = idx >> 12;
  int k = sg*32 + ((lane >> 4) & 3)*8 + i;
  int c16 = lane & 15;
  float wv;
  if (t < 16) wv = wS1[k*256 + t*16 + c16];
  else        wv = wF1[k*128 + (t-16)*16 + c16];
  u16 h = f2bf(wv);
  float lo = wv - bf2f(h);
  wswH[idx] = h;
  wswL[idx] = f2bf(lo);
}

// ---------------- scores via split-bf16 MFMA ----------------
// 512 thr (8 waves), 64 nodes/block, N-dim 384 cols (24 tiles of 16), K=256.
// Wave w owns n-tiles {3w,3w+1,3w+2} x all 4 m-tiles. acc = 12 subtiles (48 VGPR).
// x staged in LDS as hi/lo bf16, XOR-swizzled 16B units; weights from pre-swizzled L2.
__global__ __launch_bounds__(512, 4) void k_scores_mfma(
    const float* __restrict__ x, const int* __restrict__ deg,
    const u16* __restrict__ wswH, const u16* __restrict__ wswL,
    const float* __restrict__ bS1, const float* __restrict__ wS2, const float* __restrict__ bS2,
    const float* __restrict__ bF1, const float* __restrict__ wF2, const float* __restrict__ bF2,
    const float* __restrict__ s1bf, const float* __restrict__ scalf,
    float* __restrict__ s32, u64* __restrict__ keys, int N)
{
  __shared__ u16 xsh[2][4096];     // [buf][row*8 + swz(seg)] 16B units of 8 bf16
  __shared__ u16 xsl[2][4096];
  __shared__ float dnsh[64];
  __shared__ float part_s[64][9];
  __shared__ float part_f[64][9];

  const int tid  = threadIdx.x;
  const int lane = tid & 63;
  const int w    = tid >> 6;
  const int node0 = blockIdx.x * 64;

  if (tid < 64){
    int node = node0 + tid;
    dnsh[tid] = (node < N) ? ((float)deg[node] * scalf[2]) : 0.0f;
  }

  const int row_st = tid >> 3;          // 0..63
  const int seg_st = tid & 7;           // 0..7 (8 bf16 per seg)
  const int unit_w = row_st*8 + (seg_st ^ (row_st & 7));
  const float* srcbase = x + (size_t)(node0 + row_st)*D + seg_st*8;
  const bool rv = (node0 + row_st) < N;

  f32x4 acc[4][3];
  #pragma unroll
  for (int m = 0; m < 4; ++m)
    #pragma unroll
    for (int n = 0; n < 3; ++n) acc[m][n] = (f32x4){0.f,0.f,0.f,0.f};

  float xr[8];
  {
    if (rv){
      float4 a = *(const float4*)(srcbase);
      float4 b = *(const float4*)(srcbase + 4);
      xr[0]=a.x; xr[1]=a.y; xr[2]=a.z; xr[3]=a.w;
      xr[4]=b.x; xr[5]=b.y; xr[6]=b.z; xr[7]=b.w;
    } else {
      #pragma unroll
      for (int i = 0; i < 8; ++i) xr[i] = 0.f;
    }
  }

  #pragma unroll
  for (int c = 0; c < 4; ++c){
    const int pb = c & 1;
    // ---- pack & stage chunk c ----
    {
      u16 h[8];
      #pragma unroll
      for (int i = 0; i < 8; ++i) h[i] = f2bf(xr[i]);
      uint4 H; H.x = (u32)h[0] | ((u32)h[1]<<16); H.y = (u32)h[2] | ((u32)h[3]<<16);
               H.z = (u32)h[4] | ((u32)h[5]<<16); H.w = (u32)h[6] | ((u32)h[7]<<16);
      u16 l[8];
      #pragma unroll
      for (int i = 0; i < 8; ++i) l[i] = f2bf(xr[i] - bf2f(h[i]));
      uint4 L; L.x = (u32)l[0] | ((u32)l[1]<<16); L.y = (u32)l[2] | ((u32)l[3]<<16);
               L.z = (u32)l[4] | ((u32)l[5]<<16); L.w = (u32)l[6] | ((u32)l[7]<<16);
      *(uint4*)&xsh[pb][unit_w*8] = H;
      *(uint4*)&xsl[pb][unit_w*8] = L;
    }
    // ---- prefetch chunk c+1 (in flight across barrier + compute) ----
    if (c < 3){
      const float* sn = srcbase + (c+1)*64;
      if (rv){
        float4 a = *(const float4*)(sn);
        float4 b = *(const float4*)(sn + 4);
        xr[0]=a.x; xr[1]=a.y; xr[2]=a.z; xr[3]=a.w;
        xr[4]=b.x; xr[5]=b.y; xr[6]=b.z; xr[7]=b.w;
      }
    }
    __syncthreads();
    // ---- compute 2 k-steps from buf pb ----
    #pragma unroll
    for (int s = 0; s < 2; ++s){
      const int sg = c*2 + s;
      bf16x8 ah[4], al[4];
      #pragma unroll
      for (int mt = 0; mt < 4; ++mt){
        int row = mt*16 + (lane & 15);
        int seg = s*4 + (lane >> 4);
        int un  = row*8 + (seg ^ (row & 7));
        ah[mt] = *(const bf16x8*)&xsh[pb][un*8];
        al[mt] = *(const bf16x8*)&xsl[pb][un*8];
      }
      const int t0 = w*3;
      size_t o0 = ((size_t)(t0*8 + sg)*64 + lane)*8;
      bf16x8 bh = *(const bf16x8*)&wswH[o0];
      bf16x8 bl = *(const bf16x8*)&wswL[o0];
      #pragma unroll
      for (int nt = 0; nt < 3; ++nt){
        bf16x8 nbh = bh, nbl = bl;
        if (nt < 2){
          size_t on = ((size_t)((t0+nt+1)*8 + sg)*64 + lane)*8;
          nbh = *(const bf16x8*)&wswH[on];
          nbl = *(const bf16x8*)&wswL[on];
        }
        #pragma unroll
        for (int mt = 0; mt < 4; ++mt){
          acc[mt][nt] = __builtin_amdgcn_mfma_f32_16x16x32_bf16(ah[mt], bh, acc[mt][nt], 0,0,0);
          acc[mt][nt] = __builtin_amdgcn_mfma_f32_16x16x32_bf16(al[mt], bh, acc[mt][nt], 0,0,0);
          acc[mt][nt] = __builtin_amdgcn_mfma_f32_16x16x32_bf16(ah[mt], bl, acc[mt][nt], 0,0,0);
        }
        bh = nbh; bl = nbl;
      }
    }
    __syncthreads();
  }

  // ---- epilogue: per-wave activation + column reduction ----
  float dnl[4][4];
  #pragma unroll
  for (int mt = 0; mt < 4; ++mt)
    #pragma unroll
    for (int j = 0; j < 4; ++j)
      dnl[mt][j] = dnsh[mt*16 + (lane>>4)*4 + j];

  float ps[4][4], pf[4][4];
  #pragma unroll
  for (int mt = 0; mt < 4; ++mt)
    #pragma unroll
    for (int j = 0; j < 4; ++j){ ps[mt][j] = 0.f; pf[mt][j] = 0.f; }

  #pragma unroll
  for (int nt = 0; nt < 3; ++nt){
    const int t = w*3 + nt;
    const int c16 = lane & 15;
    const bool isS = (t < 16);
    const int col = isS ? t*16 + c16 : (t-16)*16 + c16;
    const float bias = isS ? bS1[col] : bF1[col];
    const float sbv  = isS ? s1bf[col] : 0.f;
    const float vv   = isS ? wS2[col] : wF2[col];
    #pragma unroll
    for (int mt = 0; mt < 4; ++mt){
      #pragma unroll
      for (int j = 0; j < 4; ++j){
        float v = acc[mt][nt][j] + bias + dnl[mt][j]*sbv;
        v = lreluf(v) * vv;
        v += __shfl_xor(v, 1);
        v += __shfl_xor(v, 2);
        v += __shfl_xor(v, 4);
        v += __shfl_xor(v, 8);
        if (isS) ps[mt][j] += v; else pf[mt][j] += v;
      }
    }
  }
  if ((lane & 15) == 0){
    #pragma unroll
    for (int mt = 0; mt < 4; ++mt)
      #pragma unroll
      for (int j = 0; j < 4; ++j){
        int row = mt*16 + (lane>>4)*4 + j;
        part_s[row][w] = ps[mt][j];
        part_f[row][w] = pf[mt][j];
      }
  }
  __syncthreads();
  if (tid < 64){
    int node = node0 + tid;
    if (node < N){
      float sv = 0.f, fv = 0.f;
      #pragma unroll
      for (int ww = 0; ww < 8; ++ww){ sv += part_s[tid][ww]; fv += part_f[tid][ww]; }
      float sc = scalf[0]*(sv + bS2[0]) + scalf[1]*(fv + bF2[0]);
      s32[node] = sc;
      u32 bits = __float_as_uint(sc);
      u32 ord = (bits >> 31) ? ~bits : (bits | 0x80000000u);
      keys[node] = ((u64)(~ord) << 32) | (u32)node;
    }
  }
}

__global__ void k_padkeys(u64* __restrict__ keys, int N, int SORTN){
  int i = N + blockIdx.x*blockDim.x + threadIdx.x;
  if (i < SORTN) keys[i] = ~0ULL;
}

// ---------------- bitonic sort on packed u64 (plain ascending compare) ----------------
__global__ __launch_bounds__(1024) void k_bsort_local8k(u64* __restrict__ keys){
  __shared__ u64 sk[8192];
  const int tid = threadIdx.x;
  const int base = blockIdx.x * 8192;
  #pragma unroll
  for (int e = 0; e < 8; ++e) sk[tid + e*1024] = keys[base + tid + e*1024];
  __syncthreads();
  for (int size = 2; size <= 8192; size <<= 1){
    for (int stride = size >> 1; stride > 0; stride >>= 1){
      #pragma unroll
      for (int pp = 0; pp < 4; ++pp){
        int p  = tid + pp*1024;
        int i  = 2*p - (p & (stride-1));
        int jj = i + stride;
        bool up = (((base + i) & size) == 0);
        u64 ki = sk[i], kj = sk[jj];
        if ((ki > kj) == up){ sk[i] = kj; sk[jj] = ki; }
      }
      __syncthreads();
    }
  }
  #pragma unroll
  for (int e = 0; e < 8; ++e) keys[base + tid + e*1024] = sk[tid + e*1024];
}

__global__ __launch_bounds__(1024) void k_bmerge_local8k(u64* __restrict__ keys, int size){
  __shared__ u64 sk[8192];
  const int tid = threadIdx.x;
  const int base = blockIdx.x * 8192;
  #pragma unroll
  for (int e = 0; e < 8; ++e) sk[tid + e*1024] = keys[base + tid + e*1024];
  __syncthreads();
  for (int stride = 4096; stride > 0; stride >>= 1){
    #pragma unroll
    for (int pp = 0; pp < 4; ++pp){
      int p  = tid + pp*1024;
      int i  = 2*p - (p & (stride-1));
      int jj = i + stride;
      bool up = (((base + i) & size) == 0);
      u64 ki = sk[i], kj = sk[jj];
      if ((ki > kj) == up){ sk[i] = kj; sk[jj] = ki; }
    }
    __syncthreads();
  }
  #pragma unroll
  for (int e = 0; e < 8; ++e) keys[base + tid + e*1024] = sk[tid + e*1024];
}

// NS bitonic-merge stages (strides stride..stride>>(NS-1)) in one launch.
// Thread owns 2^NS elements spaced smin apart; requires smin >= 8192 tile handled later.
template<int NS>
__global__ void k_bpassM(u64* __restrict__ keys, int size, int stride){
  const int G = 1 << NS;
  u32 t = blockIdx.x*blockDim.x + threadIdx.x;
  u32 smin = (u32)stride >> (NS-1);
  u32 i0 = (t/smin)*(smin << NS) + (t % smin);
  u64 v[G];
  #pragma unroll
  for (int j = 0; j < G; ++j) v[j] = keys[i0 + (u32)j*smin];
  bool up = ((i0 & (u32)size) == 0);
  #pragma unroll
  for (int b = (G>>1); b >= 1; b >>= 1){
    #pragma unroll
    for (int j = 0; j < G; ++j){
      if ((j & b) == 0){
        u64 a = v[j], cc = v[j|b];
        if ((a > cc) == up){ v[j] = cc; v[j|b] = a; }
      }
    }
  }
  #pragma unroll
  for (int j = 0; j < G; ++j) keys[i0 + (u32)j*smin] = v[j];
}

// ---------------- f64 band refinement around rank-k cutoff ----------------
__global__ void kr_cut(const u64* __restrict__ keys, int k, float* __restrict__ cutbuf,
                       int* __restrict__ r01){
  if (threadIdx.x == 0 && blockIdx.x == 0){
    u32 key32 = (u32)(keys[k-1] >> 32);
    u32 ord = ~key32;
    u32 u = (ord & 0x80000000u) ? (ord ^ 0x80000000u) : ~ord;
    float c = __uint_as_float(u);
    cutbuf[0] = c - BAND_DELTA;
    cutbuf[1] = c + BAND_DELTA;
    r01[0] = 0x7FFFFFFF;
    r01[1] = -1;
  }
}

__global__ __launch_bounds__(256) void kr_rescore(
    const u64* __restrict__ keys, const float* __restrict__ s32,
    const float* __restrict__ x, const int* __restrict__ deg,
    const float* __restrict__ wS1, const float* __restrict__ bS1,
    const float* __restrict__ wS2, const float* __restrict__ bS2,
    const float* __restrict__ wF1, const float* __restrict__ bF1,
    const float* __restrict__ wF2, const float* __restrict__ bF2,
    const double* __restrict__ s1b, const double* __restrict__ scal,
    const float* __restrict__ cutbuf, int* __restrict__ r01,
    double* __restrict__ bandS, int k, int N)
{
  const int r = k - BAND_W + blockIdx.x;
  if (r < 0 || r >= N) return;
  const int node = (int)(u32)(keys[r] & 0xFFFFFFFFULL);
  const float s = s32[node];
  if (s < cutbuf[0] || s > cutbuf[1]) return;

  const int tid = threadIdx.x;
  if (tid == 0){ atomicMin(&r01[0], r); atomicMax(&r01[1], r); }

  __shared__ float xr[256];
  __shared__ double rsp[4], rfp[4];
  xr[tid] = x[(size_t)node*D + tid];
  __syncthreads();

  const int j = tid;
  double accA = (double)bS1[j] + ((double)deg[node]/scal[2]) * s1b[j];
  double accB = (j < 128) ? (double)bF1[j] : 0.0;
  for (int rr = 0; rr < D; ++rr){
    double xv = (double)xr[rr];
    accA = fma(xv, (double)wS1[rr*D + j], accA);
    if (j < 128) accB = fma(xv, (double)wF1[rr*128 + j], accB);
  }
  double sp = lrelu(accA) * (double)wS2[j];
  double fp = (j < 128) ? lrelu(accB) * (double)wF2[j] : 0.0;

  const int lane = tid & 63, wave = tid >> 6;
  #pragma unroll
  for (int off = 32; off > 0; off >>= 1){
    sp += __shfl_down(sp, off);
    fp += __shfl_down(fp, off);
  }
  if (lane == 0){ rsp[wave] = sp; rfp[wave] = fp; }
  __syncthreads();
  if (tid == 0){
    double SP = rsp[0]+rsp[1]+rsp[2]+rsp[3];
    double FP = rfp[0]+rfp[1]+rfp[2]+rfp[3];
    bandS[blockIdx.x] = scal[0]*(SP + (double)bS2[0]) + scal[1]*(FP + (double)bF2[0]);
  }
}

__global__ __launch_bounds__(1024) void kr_bandsort(u64* __restrict__ keys,
    const double* __restrict__ bandS, const int* __restrict__ r01, int k){
  __shared__ double bs[8192];
  __shared__ int bi[8192];
  const int r0 = r01[0], r1 = r01[1];
  int nb = r1 - r0 + 1;
  if (nb <= 1) return;
  if (nb > 8192) nb = 8192;
  int M = 1; while (M < nb) M <<= 1;
  const int tid = threadIdx.x;
  const int sbase = r0 - (k - BAND_W);
  for (int m = tid; m < M; m += 1024){
    if (m < nb){ bs[m] = bandS[sbase + m]; bi[m] = (int)(u32)(keys[r0+m] & 0xFFFFFFFFULL); }
    else       { bs[m] = -1.0/0.0;         bi[m] = 0x7FFFFFFF; }
  }
  __syncthreads();
  for (int size = 2; size <= M; size <<= 1){
    for (int stride = size >> 1; stride > 0; stride >>= 1){
      for (int p = tid; p < (M >> 1); p += 1024){
        int i = 2*p - (p & (stride-1));
        int jj = i + stride;
        bool up = ((i & size) == 0);
        double si_ = bs[i], sj = bs[jj];
        int ii = bi[i], ij = bi[jj];
        bool gt = (si_ < sj) || (si_ == sj && ii > ij);
        if (gt == up){ bs[i]=sj; bs[jj]=si_; bi[i]=ij; bi[jj]=ii; }
      }
      __syncthreads();
    }
  }
  for (int m = tid; m < nb; m += 1024)
    keys[r0+m] = (u64)(u32)bi[m];
}

// ---------------- post-topk: node_map + topk_scores fused ----------------
__global__ void k_finalize(const u64* __restrict__ keys, const float* __restrict__ s32,
                           int k, int* __restrict__ nmap, float* __restrict__ outS){
  int p = blockIdx.x*blockDim.x + threadIdx.x;
  if (p < k){
    int node = (int)(u32)(keys[p] & 0xFFFFFFFFULL);
    nmap[node] = p;
    outS[p] = s32[node];
  }
}

// register-tiled f32 GEMM: 64 rows/block, thread = 16 rows x 4 cols
__global__ __launch_bounds__(256) void k_xpool(const float* __restrict__ x, const u64* __restrict__ keys,
    const float* __restrict__ wP, const float* __restrict__ bP, float* __restrict__ out, int kk){
  __shared__ float xp[256][64];   // 64 KiB, [k][row]
  const int tid = threadIdx.x;
  const int p0 = blockIdx.x * 64;
  if (p0 >= kk) return;
  const int a16 = (tid >> 6) * 16;
  const int cg = tid & 63;

  {
    const int rl = tid & 63, kseg = tid >> 6;
    int p = p0 + rl; if (p >= kk) p = kk - 1;
    int node = (int)(u32)(keys[p] & 0xFFFFFFFFULL);
    const float* src = x + (size_t)node*D + kseg*64;
    #pragma unroll
    for (int i4 = 0; i4 < 16; ++i4){
      float4 f = *(const float4*)(src + i4*4);
      const int kb = kseg*64 + i4*4;
      xp[kb+0][rl] = f.x; xp[kb+1][rl] = f.y; xp[kb+2][rl] = f.z; xp[kb+3][rl] = f.w;
    }
  }
  __syncthreads();

  float acc[16][4];
  {
    const float bq0 = bP[cg], bq1 = bP[cg+64], bq2 = bP[cg+128], bq3 = bP[cg+192];
    #pragma unroll
    for (int n = 0; n < 16; ++n){ acc[n][0]=bq0; acc[n][1]=bq1; acc[n][2]=bq2; acc[n][3]=bq3; }
  }
  const float* pP = wP + cg;
  float w0 = pP[0], w1 = pP[64], w2 = pP[128], w3 = pP[192];
  for (int kk2 = 0; kk2 < 256; ++kk2){
    const float* qP = (kk2 < 255) ? pP + 256 : pP;
    float u0 = qP[0], u1 = qP[64], u2 = qP[128], u3 = qP[192];
    float4 t0 = *(const float4*)&xp[kk2][a16+0];
    float4 t1 = *(const float4*)&xp[kk2][a16+4];
    float4 t2 = *(const float4*)&xp[kk2][a16+8];
    float4 t3 = *(const float4*)&xp[kk2][a16+12];
    float xv[16] = {t0.x,t0.y,t0.z,t0.w, t1.x,t1.y,t1.z,t1.w,
                    t2.x,t2.y,t2.z,t2.w, t3.x,t3.y,t3.z,t3.w};
    #pragma unroll
    for (int n = 0; n < 16; ++n){
      acc[n][0] = fmaf(xv[n], w0, acc[n][0]);
      acc[n][1] = fmaf(xv[n], w1, acc[n][1]);
      acc[n][2] = fmaf(xv[n], w2, acc[n][2]);
      acc[n][3] = fmaf(xv[n], w3, acc[n][3]);
    }
    w0=u0; w1=u1; w2=u2; w3=u3; pP = qP;
  }
  #pragma unroll
  for (int n = 0; n < 16; ++n){
    int p = p0 + a16 + n;
    if (p < kk){
      float* o = out + (size_t)p*D + cg;
      o[0]   = lreluf(acc[n][0]);
      o[64]  = lreluf(acc[n][1]);
      o[128] = lreluf(acc[n][2]);
      o[192] = lreluf(acc[n][3]);
    }
  }
}

// ---------------- edge remap + stable compaction ----------------
__global__ void k_efill(float* __restrict__ e, long long n2){
  long long stride = (long long)gridDim.x*blockDim.x;
  for (long long i = (long long)blockIdx.x*blockDim.x + threadIdx.x; i < n2; i += stride)
    e[i] = -1.0f;
}

__global__ __launch_bounds__(256) void k_ecount(const int* __restrict__ erow, const int* __restrict__ ecol,
    const int* __restrict__ nmap, int E, int* __restrict__ bcount){
  __shared__ int sc[256];
  const int tid = threadIdx.x;
  const int base = blockIdx.x*EBLK + tid*ECH;
  int cnt = 0;
  #pragma unroll
  for (int q = 0; q < ECH; ++q){
    int e = base + q;
    if (e < E){
      if (nmap[erow[e]] >= 0 && nmap[ecol[e]] >= 0) cnt++;
    }
  }
  sc[tid] = cnt; __syncthreads();
  for (int s = 128; s > 0; s >>= 1){
    if (tid < s) sc[tid] += sc[tid+s];
    __syncthreads();
  }
  if (tid == 0) bcount[blockIdx.x] = sc[0];
}

__global__ __launch_bounds__(1024) void k_escan(const int* __restrict__ bcount, int nblk, int* __restrict__ boff){
  __shared__ int sh[1024];
  const int tid = threadIdx.x;
  int carry = 0;
  for (int s = 0; s < nblk; s += 1024){
    int v = (s + tid < nblk) ? bcount[s+tid] : 0;
    sh[tid] = v; __syncthreads();
    for (int d = 1; d < 1024; d <<= 1){
      int t = (tid >= d) ? sh[tid-d] : 0;
      __syncthreads();
      sh[tid] += t;
      __syncthreads();
    }
    if (s + tid < nblk) boff[s+tid] = carry + sh[tid] - v;
    carry += sh[1023];
    __syncthreads();
  }
}

__global__ __launch_bounds__(256) void k_escatter(const int* __restrict__ erow, const int* __restrict__ ecol,
    const int* __restrict__ nmap, int E, const int* __restrict__ boff,
    float* __restrict__ outR, float* __restrict__ outC){
  __shared__ int sc[256];
  const int tid = threadIdx.x;
  const int base = blockIdx.x*EBLK + tid*ECH;
  int mr[ECH], mc[ECH];
  int cnt = 0;
  #pragma unroll
  for (int q = 0; q < ECH; ++q){
    int e = base + q;
    int a = -1, b = -1;
    if (e < E){ a = nmap[erow[e]]; b = nmap[ecol[e]]; }
    mr[q] = a; mc[q] = b;
    if (a >= 0 && b >= 0) cnt++;
  }
  sc[tid] = cnt; __syncthreads();
  int v = cnt;
  for (int d = 1; d < 256; d <<= 1){
    int t = (tid >= d) ? sc[tid-d] : 0;
    __syncthreads();
    sc[tid] += t;
    __syncthreads();
  }
  int pos = boff[blockIdx.x] + sc[tid] - v;
  #pragma unroll
  for (int q = 0; q < ECH; ++q){
    if (mr[q] >= 0 && mc[q] >= 0){
      outR[pos] = (float)mr[q];
      outC[pos] = (float)mc[q];
      pos++;
    }
  }
}

// ---------------- host ----------------
extern "C" void kernel_launch(void* const* d_in, const int* in_sizes, int n_in,
                              void* d_out, int out_size, void* d_ws, size_t ws_size,
                              hipStream_t stream)
{
  const float* x   = (const float*)d_in[0];
  const int*   ei  = (const int*)d_in[1];
  const float* wS1 = (const float*)d_in[2];
  const float* bS1 = (const float*)d_in[3];
  const float* wS2 = (const float*)d_in[4];
  const float* bS2 = (const float*)d_in[5];
  const float* wF1 = (const float*)d_in[6];
  const float* bF1 = (const float*)d_in[7];
  const float* wF2 = (const float*)d_in[8];
  const float* bF2 = (const float*)d_in[9];
  const float* wP  = (const float*)d_in[10];
  const float* bP  = (const float*)d_in[11];
  const float* alpha = (const float*)d_in[12];
  const float* beta  = (const float*)d_in[13];
  (void)n_in; (void)out_size; (void)ws_size;

  const int N = in_sizes[0] / D;
  const int E = in_sizes[1] / 2;
  int k = (int)(0.5 * (double)N); if (k < 1) k = 1;
  int SORTN = 8192; while (SORTN < N) SORTN <<= 1;   // 262144 for N=200000
  const int nblk_e = (E + EBLK - 1) / EBLK;

  char* w = (char*)d_ws;
  size_t off = 0;
  auto alloc = [&](size_t bytes)->char*{
    char* p = w + off;
    off = (off + bytes + 255) & ~(size_t)255;
    return p;
  };
  float*  s32    = (float*) alloc((size_t)N*4);
  u64*    keys   = (u64*)   alloc((size_t)SORTN*8);
  int*    deg    = (int*)   alloc((size_t)N*4);
  int*    nmap   = (int*)   alloc((size_t)N*4);
  double* s1b    = (double*)alloc((size_t)D*8);
  float*  s1bf   = (float*) alloc((size_t)D*4);
  double* scal   = (double*)alloc(4*8);
  float*  scalf  = (float*) alloc(4*4);
  u64*    sumsq  = (u64*)   alloc(8);
  float*  cutbuf = (float*) alloc(2*4);
  int*    r01    = (int*)   alloc(2*4);
  double* bandS  = (double*)alloc((size_t)2*BAND_W*8);
  u16*    wswH   = (u16*)   alloc((size_t)98304*2);
  u16*    wswL   = (u16*)   alloc((size_t)98304*2);
  int*    bcount = (int*)   alloc((size_t)nblk_e*4);
  int*    boff   = (int*)   alloc((size_t)nblk_e*4);

  float* outX  = (float*)d_out;
  float* outER = outX  + (size_t)k*D;
  float* outEC = outER + (size_t)E;
  float* outS  = outEC + (size_t)E;

  hipMemsetAsync(deg,   0,    (size_t)N*4, stream);
  hipMemsetAsync(sumsq, 0,    8,           stream);
  hipMemsetAsync(nmap,  0xFF, (size_t)N*4, stream);   // = -1

  k_degree<<<2048, 256, 0, stream>>>(ei, E, deg);
  k_degsq <<<1024, 256, 0, stream>>>(deg, N, sumsq);
  k_prep  <<<1,    D,   0, stream>>>(wS1, alpha, beta, sumsq, s1b, scal, s1bf, scalf);
  k_wsw   <<<384,  256, 0, stream>>>(wS1, wF1, wswH, wswL);
  k_scores_mfma<<<(N + 63)/64, 512, 0, stream>>>(x, deg, wswH, wswL,
                                                 bS1, wS2, bS2, bF1, wF2, bF2,
                                                 s1bf, scalf, s32, keys, N);
  k_padkeys<<<(SORTN - N + 255)/256, 256, 0, stream>>>(keys, N, SORTN);

  // sort packed keys ascending (= score desc, idx asc)
  k_bsort_local8k<<<SORTN/8192, 1024, 0, stream>>>(keys);
  for (int size = 16384; size <= SORTN; size <<= 1){
    int stride = size >> 1;
    while (stride >= 8192){
      int ns = 1;
      while (ns < 4 && (stride >> ns) >= 8192) ns++;
      switch (ns){
        case 1: k_bpassM<1><<<SORTN/2/256,  256, 0, stream>>>(keys, size, stride); break;
        case 2: k_bpassM<2><<<SORTN/4/256,  256, 0, stream>>>(keys, size, stride); break;
        case 3: k_bpassM<3><<<SORTN/8/256,  256, 0, stream>>>(keys, size, stride); break;
        default:k_bpassM<4><<<SORTN/16/256, 256, 0, stream>>>(keys, size, stride); break;
      }
      stride >>= ns;
    }
    k_bmerge_local8k<<<SORTN/8192, 1024, 0, stream>>>(keys, size);
  }

  // f64 band refinement around the cutoff
  kr_cut     <<<1, 64, 0, stream>>>(keys, k, cutbuf, r01);
  kr_rescore <<<2*BAND_W, 256, 0, stream>>>(keys, s32, x, deg, wS1,bS1,wS2,bS2,
                                            wF1,bF1,wF2,bF2, s1b, scal,
                                            cutbuf, r01, bandS, k, N);
  kr_bandsort<<<1, 1024, 0, stream>>>(keys, bandS, r01, k);

  k_finalize<<<(k+255)/256, 256, 0, stream>>>(keys, s32, k, nmap, outS);
  k_xpool   <<<(k+63)/64, 256, 0, stream>>>(x, keys, wP, bP, outX, k);
  k_efill   <<<2048, 256, 0, stream>>>(outER, (long long)2*E);
  k_ecount  <<<nblk_e, 256, 0, stream>>>(ei, ei+E, nmap, E, bcount);
  k_escan   <<<1, 1024, 0, stream>>>(bcount, nblk_e, boff);
  k_escatter<<<nblk_e, 256, 0, stream>>>(ei, ei+E, nmap, E, boff, outER, outEC);
}

// Round 5
// 979.600 us; speedup vs baseline: 3.6461x; 1.1432x over previous
//
#include <hip/hip_runtime.h>
#include <math.h>

typedef unsigned long long u64;
typedef unsigned int u32;
typedef unsigned short u16;
typedef __attribute__((ext_vector_type(8))) short bf16x8;
typedef __attribute__((ext_vector_type(4))) float f32x4;

#define D   256
#define ECH 16          // edges per thread
#define EBLK (256*ECH)  // edges per block
#define BAND_W 4096     // rank window half-width around k for f64 refinement
#define BAND_DELTA 1e-3f

__device__ __forceinline__ double lrelu(double v){ return v > 0.0 ? v : 0.2*v; }
__device__ __forceinline__ float  lreluf(float v){ return v > 0.0f ? v : 0.2f*v; }

__device__ __forceinline__ u16 f2bf(float f){
  union{float f; u32 u;} v; v.f = f;
  u32 r = v.u + 0x7FFFu + ((v.u >> 16) & 1u);   // RNE
  return (u16)(r >> 16);
}
__device__ __forceinline__ float bf2f(u16 b){
  union{u32 u; float f;} v; v.u = ((u32)b) << 16; return v.f;
}

// ---------------- degree: XCD-replicated near-atomics ----------------
// deg8[xcd][node]: all writers of replica r are blocks on XCD r, which share
// that XCD's L2 -> workgroup-scope atomic (no sc1) executes as near-atomic in
// local L2 and is coherent among its writers. Final deg = sum of replicas
// (exact integer sum -> deterministic regardless of block->XCD mapping).
__global__ void k_degree8(const int* __restrict__ row, int E, u32* __restrict__ deg8, int N){
  u32 xcc;
  asm volatile("s_getreg_b32 %0, hwreg(HW_REG_XCC_ID)" : "=s"(xcc));
  u32* mydeg = deg8 + (size_t)(xcc & 7) * (size_t)N;
  int stride = gridDim.x*blockDim.x;
  for (int i = blockIdx.x*blockDim.x + threadIdx.x; i < E; i += stride)
    __hip_atomic_fetch_add(&mydeg[row[i]], 1u, __ATOMIC_RELAXED, __HIP_MEMORY_SCOPE_WORKGROUP);
}

// reduce replicas + fused deg^2 sum
__global__ void k_degred(const u32* __restrict__ deg8, int N,
                         int* __restrict__ deg, u64* __restrict__ out){
  __shared__ u64 sh[256];
  u64 local = 0;
  int stride = gridDim.x*blockDim.x;
  for (int i = blockIdx.x*blockDim.x + threadIdx.x; i < N; i += stride){
    u32 s = 0;
    #pragma unroll
    for (int r = 0; r < 8; ++r) s += deg8[(size_t)r*N + i];
    deg[i] = (int)s;
    local += (u64)s * (u64)s;
  }
  sh[threadIdx.x] = local; __syncthreads();
  for (int s = 128; s > 0; s >>= 1){
    if (threadIdx.x < s) sh[threadIdx.x] += sh[threadIdx.x+s];
    __syncthreads();
  }
  if (threadIdx.x == 0) atomicAdd(out, sh[0]);
}

// s1b[j] = sum_{r=256..511} w_s1[r][j]; plus scalar weights (f64 + f32 copies)
__global__ void k_prep(const float* __restrict__ wS1, const float* __restrict__ alpha,
                       const float* __restrict__ beta, const u64* __restrict__ sumsq,
                       double* __restrict__ s1b, double* __restrict__ scal,
                       float* __restrict__ s1bf, float* __restrict__ scalf){
  int j = threadIdx.x;
  double s = 0.0;
  for (int r = 0; r < D; ++r) s += (double)wS1[(D + r)*D + j];
  s1b[j] = s;
  s1bf[j] = (float)s;
  if (j == 0){
    double a = 1.0/(1.0 + exp(-(double)alpha[0]));
    double b = 1.0/(1.0 + exp(-(double)beta[0]));
    scal[0] = a/(a+b);
    scal[1] = b/(a+b);
    double dn = sqrt((double)(*sumsq));
    scal[2] = dn > 1e-12 ? dn : 1e-12;
    scalf[0] = (float)scal[0];
    scalf[1] = (float)scal[1];
    scalf[2] = (float)(1.0/scal[2]);
  }
}

// ---------------- weight pre-swizzle into MFMA B-fragment order (hi/lo bf16) ---------
// wsw[((t*8 + sg)*64 + lane)*8 + i] = w[k][col], k = sg*32 + (lane>>4)*8 + i,
// col = t<16 ? t*16+(lane&15) (wS1 top)  :  (t-16)*16+(lane&15) (wF1)
__global__ void k_wsw(const float* __restrict__ wS1, const float* __restrict__ wF1,
                      u16* __restrict__ wswH, u16* __restrict__ wswL){
  int idx = blockIdx.x*blockDim.x + threadIdx.x;   // 24*8*64*8 = 98304
  int i    = idx & 7;
  int lane = (idx >> 3) & 63;
  int sg   = (idx >> 9) & 7;
  int t    = idx >> 12;
  int k = sg*32 + ((lane >> 4) & 3)*8 + i;
  int c16 = lane & 15;
  float wv;
  if (t < 16) wv = wS1[k*256 + t*16 + c16];
  else        wv = wF1[k*128 + (t-16)*16 + c16];
  u16 h = f2bf(wv);
  float lo = wv - bf2f(h);
  wswH[idx] = h;
  wswL[idx] = f2bf(lo);
}

// same for wP: 16 tiles, col = t*16 + (lane&15), source wP[k*256 + col]
__global__ void k_wswP(const float* __restrict__ wP,
                       u16* __restrict__ wH, u16* __restrict__ wL){
  int idx = blockIdx.x*blockDim.x + threadIdx.x;   // 16*8*64*8 = 65536
  int i    = idx & 7;
  int lane = (idx >> 3) & 63;
  int sg   = (idx >> 9) & 7;
  int t    = idx >> 12;
  int k = sg*32 + ((lane >> 4) & 3)*8 + i;
  float wv = wP[k*256 + t*16 + (lane & 15)];
  u16 h = f2bf(wv);
  float lo = wv - bf2f(h);
  wH[idx] = h;
  wL[idx] = f2bf(lo);
}

// ---------------- scores via split-bf16 MFMA ----------------
__global__ __launch_bounds__(512, 4) void k_scores_mfma(
    const float* __restrict__ x, const int* __restrict__ deg,
    const u16* __restrict__ wswH, const u16* __restrict__ wswL,
    const float* __restrict__ bS1, const float* __restrict__ wS2, const float* __restrict__ bS2,
    const float* __restrict__ bF1, const float* __restrict__ wF2, const float* __restrict__ bF2,
    const float* __restrict__ s1bf, const float* __restrict__ scalf,
    float* __restrict__ s32, u64* __restrict__ keys, int N)
{
  __shared__ u16 xsh[2][4096];     // [buf][row*8 + swz(seg)] 16B units of 8 bf16
  __shared__ u16 xsl[2][4096];
  __shared__ float dnsh[64];
  __shared__ float part_s[64][9];
  __shared__ float part_f[64][9];

  const int tid  = threadIdx.x;
  const int lane = tid & 63;
  const int w    = tid >> 6;
  const int node0 = blockIdx.x * 64;

  if (tid < 64){
    int node = node0 + tid;
    dnsh[tid] = (node < N) ? ((float)deg[node] * scalf[2]) : 0.0f;
  }

  const int row_st = tid >> 3;          // 0..63
  const int seg_st = tid & 7;           // 0..7 (8 bf16 per seg)
  const int unit_w = row_st*8 + (seg_st ^ (row_st & 7));
  const float* srcbase = x + (size_t)(node0 + row_st)*D + seg_st*8;
  const bool rv = (node0 + row_st) < N;

  f32x4 acc[4][3];
  #pragma unroll
  for (int m = 0; m < 4; ++m)
    #pragma unroll
    for (int n = 0; n < 3; ++n) acc[m][n] = (f32x4){0.f,0.f,0.f,0.f};

  float xr[8];
  {
    if (rv){
      float4 a = *(const float4*)(srcbase);
      float4 b = *(const float4*)(srcbase + 4);
      xr[0]=a.x; xr[1]=a.y; xr[2]=a.z; xr[3]=a.w;
      xr[4]=b.x; xr[5]=b.y; xr[6]=b.z; xr[7]=b.w;
    } else {
      #pragma unroll
      for (int i = 0; i < 8; ++i) xr[i] = 0.f;
    }
  }

  #pragma unroll
  for (int c = 0; c < 4; ++c){
    const int pb = c & 1;
    {
      u16 h[8];
      #pragma unroll
      for (int i = 0; i < 8; ++i) h[i] = f2bf(xr[i]);
      uint4 H; H.x = (u32)h[0] | ((u32)h[1]<<16); H.y = (u32)h[2] | ((u32)h[3]<<16);
               H.z = (u32)h[4] | ((u32)h[5]<<16); H.w = (u32)h[6] | ((u32)h[7]<<16);
      u16 l[8];
      #pragma unroll
      for (int i = 0; i < 8; ++i) l[i] = f2bf(xr[i] - bf2f(h[i]));
      uint4 L; L.x = (u32)l[0] | ((u32)l[1]<<16); L.y = (u32)l[2] | ((u32)l[3]<<16);
               L.z = (u32)l[4] | ((u32)l[5]<<16); L.w = (u32)l[6] | ((u32)l[7]<<16);
      *(uint4*)&xsh[pb][unit_w*8] = H;
      *(uint4*)&xsl[pb][unit_w*8] = L;
    }
    if (c < 3){
      const float* sn = srcbase + (c+1)*64;
      if (rv){
        float4 a = *(const float4*)(sn);
        float4 b = *(const float4*)(sn + 4);
        xr[0]=a.x; xr[1]=a.y; xr[2]=a.z; xr[3]=a.w;
        xr[4]=b.x; xr[5]=b.y; xr[6]=b.z; xr[7]=b.w;
      }
    }
    __syncthreads();
    #pragma unroll
    for (int s = 0; s < 2; ++s){
      const int sg = c*2 + s;
      bf16x8 ah[4], al[4];
      #pragma unroll
      for (int mt = 0; mt < 4; ++mt){
        int row = mt*16 + (lane & 15);
        int seg = s*4 + (lane >> 4);
        int un  = row*8 + (seg ^ (row & 7));
        ah[mt] = *(const bf16x8*)&xsh[pb][un*8];
        al[mt] = *(const bf16x8*)&xsl[pb][un*8];
      }
      const int t0 = w*3;
      size_t o0 = ((size_t)(t0*8 + sg)*64 + lane)*8;
      bf16x8 bh = *(const bf16x8*)&wswH[o0];
      bf16x8 bl = *(const bf16x8*)&wswL[o0];
      #pragma unroll
      for (int nt = 0; nt < 3; ++nt){
        bf16x8 nbh = bh, nbl = bl;
        if (nt < 2){
          size_t on = ((size_t)((t0+nt+1)*8 + sg)*64 + lane)*8;
          nbh = *(const bf16x8*)&wswH[on];
          nbl = *(const bf16x8*)&wswL[on];
        }
        #pragma unroll
        for (int mt = 0; mt < 4; ++mt){
          acc[mt][nt] = __builtin_amdgcn_mfma_f32_16x16x32_bf16(ah[mt], bh, acc[mt][nt], 0,0,0);
          acc[mt][nt] = __builtin_amdgcn_mfma_f32_16x16x32_bf16(al[mt], bh, acc[mt][nt], 0,0,0);
          acc[mt][nt] = __builtin_amdgcn_mfma_f32_16x16x32_bf16(ah[mt], bl, acc[mt][nt], 0,0,0);
        }
        bh = nbh; bl = nbl;
      }
    }
    __syncthreads();
  }

  // epilogue: per-wave activation + column reduction
  float dnl[4][4];
  #pragma unroll
  for (int mt = 0; mt < 4; ++mt)
    #pragma unroll
    for (int j = 0; j < 4; ++j)
      dnl[mt][j] = dnsh[mt*16 + (lane>>4)*4 + j];

  float ps[4][4], pf[4][4];
  #pragma unroll
  for (int mt = 0; mt < 4; ++mt)
    #pragma unroll
    for (int j = 0; j < 4; ++j){ ps[mt][j] = 0.f; pf[mt][j] = 0.f; }

  #pragma unroll
  for (int nt = 0; nt < 3; ++nt){
    const int t = w*3 + nt;
    const int c16 = lane & 15;
    const bool isS = (t < 16);
    const int col = isS ? t*16 + c16 : (t-16)*16 + c16;
    const float bias = isS ? bS1[col] : bF1[col];
    const float sbv  = isS ? s1bf[col] : 0.f;
    const float vv   = isS ? wS2[col] : wF2[col];
    #pragma unroll
    for (int mt = 0; mt < 4; ++mt){
      #pragma unroll
      for (int j = 0; j < 4; ++j){
        float v = acc[mt][nt][j] + bias + dnl[mt][j]*sbv;
        v = lreluf(v) * vv;
        v += __shfl_xor(v, 1);
        v += __shfl_xor(v, 2);
        v += __shfl_xor(v, 4);
        v += __shfl_xor(v, 8);
        if (isS) ps[mt][j] += v; else pf[mt][j] += v;
      }
    }
  }
  if ((lane & 15) == 0){
    #pragma unroll
    for (int mt = 0; mt < 4; ++mt)
      #pragma unroll
      for (int j = 0; j < 4; ++j){
        int row = mt*16 + (lane>>4)*4 + j;
        part_s[row][w] = ps[mt][j];
        part_f[row][w] = pf[mt][j];
      }
  }
  __syncthreads();
  if (tid < 64){
    int node = node0 + tid;
    if (node < N){
      float sv = 0.f, fv = 0.f;
      #pragma unroll
      for (int ww = 0; ww < 8; ++ww){ sv += part_s[tid][ww]; fv += part_f[tid][ww]; }
      float sc = scalf[0]*(sv + bS2[0]) + scalf[1]*(fv + bF2[0]);
      s32[node] = sc;
      u32 bits = __float_as_uint(sc);
      u32 ord = (bits >> 31) ? ~bits : (bits | 0x80000000u);
      keys[node] = ((u64)(~ord) << 32) | (u32)node;
    }
  }
}

__global__ void k_padkeys(u64* __restrict__ keys, int N, int SORTN){
  int i = N + blockIdx.x*blockDim.x + threadIdx.x;
  if (i < SORTN) keys[i] = ~0ULL;
}

// ---------------- bitonic sort on packed u64 ----------------
__global__ __launch_bounds__(1024) void k_bsort_local8k(u64* __restrict__ keys){
  __shared__ u64 sk[8192];
  const int tid = threadIdx.x;
  const int base = blockIdx.x * 8192;
  #pragma unroll
  for (int e = 0; e < 8; ++e) sk[tid + e*1024] = keys[base + tid + e*1024];
  __syncthreads();
  for (int size = 2; size <= 8192; size <<= 1){
    for (int stride = size >> 1; stride > 0; stride >>= 1){
      #pragma unroll
      for (int pp = 0; pp < 4; ++pp){
        int p  = tid + pp*1024;
        int i  = 2*p - (p & (stride-1));
        int jj = i + stride;
        bool up = (((base + i) & size) == 0);
        u64 ki = sk[i], kj = sk[jj];
        if ((ki > kj) == up){ sk[i] = kj; sk[jj] = ki; }
      }
      __syncthreads();
    }
  }
  #pragma unroll
  for (int e = 0; e < 8; ++e) keys[base + tid + e*1024] = sk[tid + e*1024];
}

__global__ __launch_bounds__(1024) void k_bmerge_local8k(u64* __restrict__ keys, int size){
  __shared__ u64 sk[8192];
  const int tid = threadIdx.x;
  const int base = blockIdx.x * 8192;
  #pragma unroll
  for (int e = 0; e < 8; ++e) sk[tid + e*1024] = keys[base + tid + e*1024];
  __syncthreads();
  for (int stride = 4096; stride > 0; stride >>= 1){
    #pragma unroll
    for (int pp = 0; pp < 4; ++pp){
      int p  = tid + pp*1024;
      int i  = 2*p - (p & (stride-1));
      int jj = i + stride;
      bool up = (((base + i) & size) == 0);
      u64 ki = sk[i], kj = sk[jj];
      if ((ki > kj) == up){ sk[i] = kj; sk[jj] = ki; }
    }
    __syncthreads();
  }
  #pragma unroll
  for (int e = 0; e < 8; ++e) keys[base + tid + e*1024] = sk[tid + e*1024];
}

template<int NS>
__global__ void k_bpassM(u64* __restrict__ keys, int size, int stride){
  const int G = 1 << NS;
  u32 t = blockIdx.x*blockDim.x + threadIdx.x;
  u32 smin = (u32)stride >> (NS-1);
  u32 i0 = (t/smin)*(smin << NS) + (t % smin);
  u64 v[G];
  #pragma unroll
  for (int j = 0; j < G; ++j) v[j] = keys[i0 + (u32)j*smin];
  bool up = ((i0 & (u32)size) == 0);
  #pragma unroll
  for (int b = (G>>1); b >= 1; b >>= 1){
    #pragma unroll
    for (int j = 0; j < G; ++j){
      if ((j & b) == 0){
        u64 a = v[j], cc = v[j|b];
        if ((a > cc) == up){ v[j] = cc; v[j|b] = a; }
      }
    }
  }
  #pragma unroll
  for (int j = 0; j < G; ++j) keys[i0 + (u32)j*smin] = v[j];
}

// ---------------- f64 band refinement around rank-k cutoff ----------------
__global__ void kr_cut(const u64* __restrict__ keys, int k, float* __restrict__ cutbuf,
                       int* __restrict__ r01){
  if (threadIdx.x == 0 && blockIdx.x == 0){
    u32 key32 = (u32)(keys[k-1] >> 32);
    u32 ord = ~key32;
    u32 u = (ord & 0x80000000u) ? (ord ^ 0x80000000u) : ~ord;
    float c = __uint_as_float(u);
    cutbuf[0] = c - BAND_DELTA;
    cutbuf[1] = c + BAND_DELTA;
    r01[0] = 0x7FFFFFFF;
    r01[1] = -1;
  }
}

__global__ __launch_bounds__(256) void kr_rescore(
    const u64* __restrict__ keys, const float* __restrict__ s32,
    const float* __restrict__ x, const int* __restrict__ deg,
    const float* __restrict__ wS1, const float* __restrict__ bS1,
    const float* __restrict__ wS2, const float* __restrict__ bS2,
    const float* __restrict__ wF1, const float* __restrict__ bF1,
    const float* __restrict__ wF2, const float* __restrict__ bF2,
    const double* __restrict__ s1b, const double* __restrict__ scal,
    const float* __restrict__ cutbuf, int* __restrict__ r01,
    double* __restrict__ bandS, int k, int N)
{
  const int r = k - BAND_W + blockIdx.x;
  if (r < 0 || r >= N) return;
  const int node = (int)(u32)(keys[r] & 0xFFFFFFFFULL);
  const float s = s32[node];
  if (s < cutbuf[0] || s > cutbuf[1]) return;

  const int tid = threadIdx.x;
  if (tid == 0){ atomicMin(&r01[0], r); atomicMax(&r01[1], r); }

  __shared__ float xr[256];
  __shared__ double rsp[4], rfp[4];
  xr[tid] = x[(size_t)node*D + tid];
  __syncthreads();

  const int j = tid;
  double accA = (double)bS1[j] + ((double)deg[node]/scal[2]) * s1b[j];
  double accB = (j < 128) ? (double)bF1[j] : 0.0;
  for (int rr = 0; rr < D; ++rr){
    double xv = (double)xr[rr];
    accA = fma(xv, (double)wS1[rr*D + j], accA);
    if (j < 128) accB = fma(xv, (double)wF1[rr*128 + j], accB);
  }
  double sp = lrelu(accA) * (double)wS2[j];
  double fp = (j < 128) ? lrelu(accB) * (double)wF2[j] : 0.0;

  const int lane = tid & 63, wave = tid >> 6;
  #pragma unroll
  for (int off = 32; off > 0; off >>= 1){
    sp += __shfl_down(sp, off);
    fp += __shfl_down(fp, off);
  }
  if (lane == 0){ rsp[wave] = sp; rfp[wave] = fp; }
  __syncthreads();
  if (tid == 0){
    double SP = rsp[0]+rsp[1]+rsp[2]+rsp[3];
    double FP = rfp[0]+rfp[1]+rfp[2]+rfp[3];
    bandS[blockIdx.x] = scal[0]*(SP + (double)bS2[0]) + scal[1]*(FP + (double)bF2[0]);
  }
}

__global__ __launch_bounds__(1024) void kr_bandsort(u64* __restrict__ keys,
    const double* __restrict__ bandS, const int* __restrict__ r01, int k){
  __shared__ double bs[8192];
  __shared__ int bi[8192];
  const int r0 = r01[0], r1 = r01[1];
  int nb = r1 - r0 + 1;
  if (nb <= 1) return;
  if (nb > 8192) nb = 8192;
  int M = 1; while (M < nb) M <<= 1;
  const int tid = threadIdx.x;
  const int sbase = r0 - (k - BAND_W);
  for (int m = tid; m < M; m += 1024){
    if (m < nb){ bs[m] = bandS[sbase + m]; bi[m] = (int)(u32)(keys[r0+m] & 0xFFFFFFFFULL); }
    else       { bs[m] = -1.0/0.0;         bi[m] = 0x7FFFFFFF; }
  }
  __syncthreads();
  for (int size = 2; size <= M; size <<= 1){
    for (int stride = size >> 1; stride > 0; stride >>= 1){
      for (int p = tid; p < (M >> 1); p += 1024){
        int i = 2*p - (p & (stride-1));
        int jj = i + stride;
        bool up = ((i & size) == 0);
        double si_ = bs[i], sj = bs[jj];
        int ii = bi[i], ij = bi[jj];
        bool gt = (si_ < sj) || (si_ == sj && ii > ij);
        if (gt == up){ bs[i]=sj; bs[jj]=si_; bi[i]=ij; bi[jj]=ii; }
      }
      __syncthreads();
    }
  }
  for (int m = tid; m < nb; m += 1024)
    keys[r0+m] = (u64)(u32)bi[m];
}

// ---------------- post-topk: node_map + topk_scores fused ----------------
__global__ void k_finalize(const u64* __restrict__ keys, const float* __restrict__ s32,
                           int k, int* __restrict__ nmap, float* __restrict__ outS){
  int p = blockIdx.x*blockDim.x + threadIdx.x;
  if (p < k){
    int node = (int)(u32)(keys[p] & 0xFFFFFFFFULL);
    nmap[node] = p;
    outS[p] = s32[node];
  }
}

// ---------------- x_pooled via split-bf16 MFMA ----------------
// 512 thr / 8 waves, 64 rows per block; wave owns 2 col-tiles x 4 row-tiles.
__global__ __launch_bounds__(512, 4) void k_xpool_mfma(
    const float* __restrict__ x, const u64* __restrict__ keys,
    const u16* __restrict__ wH, const u16* __restrict__ wL,
    const float* __restrict__ bP, float* __restrict__ out, int kk)
{
  __shared__ u16 xsh[2][4096];
  __shared__ u16 xsl[2][4096];

  const int tid  = threadIdx.x;
  const int lane = tid & 63;
  const int w    = tid >> 6;
  const int p0 = blockIdx.x * 64;
  if (p0 >= kk) return;

  const int row_st = tid >> 3;
  const int seg_st = tid & 7;
  const int unit_w = row_st*8 + (seg_st ^ (row_st & 7));
  int prow = p0 + row_st; if (prow >= kk) prow = kk - 1;
  const int node = (int)(u32)(keys[prow] & 0xFFFFFFFFULL);
  const float* srcbase = x + (size_t)node*D + seg_st*8;

  f32x4 acc[4][2];
  #pragma unroll
  for (int m = 0; m < 4; ++m){ acc[m][0] = (f32x4){0.f,0.f,0.f,0.f}; acc[m][1] = (f32x4){0.f,0.f,0.f,0.f}; }

  float xr[8];
  {
    float4 a = *(const float4*)(srcbase);
    float4 b = *(const float4*)(srcbase + 4);
    xr[0]=a.x; xr[1]=a.y; xr[2]=a.z; xr[3]=a.w;
    xr[4]=b.x; xr[5]=b.y; xr[6]=b.z; xr[7]=b.w;
  }

  #pragma unroll
  for (int c = 0; c < 4; ++c){
    const int pb = c & 1;
    {
      u16 h[8];
      #pragma unroll
      for (int i = 0; i < 8; ++i) h[i] = f2bf(xr[i]);
      uint4 H; H.x = (u32)h[0] | ((u32)h[1]<<16); H.y = (u32)h[2] | ((u32)h[3]<<16);
               H.z = (u32)h[4] | ((u32)h[5]<<16); H.w = (u32)h[6] | ((u32)h[7]<<16);
      u16 l[8];
      #pragma unroll
      for (int i = 0; i < 8; ++i) l[i] = f2bf(xr[i] - bf2f(h[i]));
      uint4 L; L.x = (u32)l[0] | ((u32)l[1]<<16); L.y = (u32)l[2] | ((u32)l[3]<<16);
               L.z = (u32)l[4] | ((u32)l[5]<<16); L.w = (u32)l[6] | ((u32)l[7]<<16);
      *(uint4*)&xsh[pb][unit_w*8] = H;
      *(uint4*)&xsl[pb][unit_w*8] = L;
    }
    if (c < 3){
      const float* sn = srcbase + (c+1)*64;
      float4 a = *(const float4*)(sn);
      float4 b = *(const float4*)(sn + 4);
      xr[0]=a.x; xr[1]=a.y; xr[2]=a.z; xr[3]=a.w;
      xr[4]=b.x; xr[5]=b.y; xr[6]=b.z; xr[7]=b.w;
    }
    __syncthreads();
    #pragma unroll
    for (int s = 0; s < 2; ++s){
      const int sg = c*2 + s;
      bf16x8 ah[4], al[4];
      #pragma unroll
      for (int mt = 0; mt < 4; ++mt){
        int row = mt*16 + (lane & 15);
        int seg = s*4 + (lane >> 4);
        int un  = row*8 + (seg ^ (row & 7));
        ah[mt] = *(const bf16x8*)&xsh[pb][un*8];
        al[mt] = *(const bf16x8*)&xsl[pb][un*8];
      }
      const int t0 = w*2;
      size_t o0 = ((size_t)(t0*8 + sg)*64 + lane)*8;
      bf16x8 bh = *(const bf16x8*)&wH[o0];
      bf16x8 bl = *(const bf16x8*)&wL[o0];
      #pragma unroll
      for (int nt = 0; nt < 2; ++nt){
        bf16x8 nbh = bh, nbl = bl;
        if (nt < 1){
          size_t on = ((size_t)((t0+1)*8 + sg)*64 + lane)*8;
          nbh = *(const bf16x8*)&wH[on];
          nbl = *(const bf16x8*)&wL[on];
        }
        #pragma unroll
        for (int mt = 0; mt < 4; ++mt){
          acc[mt][nt] = __builtin_amdgcn_mfma_f32_16x16x32_bf16(ah[mt], bh, acc[mt][nt], 0,0,0);
          acc[mt][nt] = __builtin_amdgcn_mfma_f32_16x16x32_bf16(al[mt], bh, acc[mt][nt], 0,0,0);
          acc[mt][nt] = __builtin_amdgcn_mfma_f32_16x16x32_bf16(ah[mt], bl, acc[mt][nt], 0,0,0);
        }
        bh = nbh; bl = nbl;
      }
    }
    __syncthreads();
  }

  // epilogue: C layout col = lane&15 (within tile), row = (lane>>4)*4 + j
  const int c16 = lane & 15, r4 = (lane >> 4)*4;
  #pragma unroll
  for (int nt = 0; nt < 2; ++nt){
    const int col = (w*2 + nt)*16 + c16;
    const float bias = bP[col];
    #pragma unroll
    for (int mt = 0; mt < 4; ++mt){
      #pragma unroll
      for (int j = 0; j < 4; ++j){
        int p = p0 + mt*16 + r4 + j;
        if (p < kk) out[(size_t)p*D + col] = lreluf(acc[mt][nt][j] + bias);
      }
    }
  }
}

// ---------------- edge remap + stable compaction ----------------
__global__ __launch_bounds__(256) void k_ecount(const int* __restrict__ erow, const int* __restrict__ ecol,
    const int* __restrict__ nmap, int E, int* __restrict__ bcount){
  __shared__ int sc[256];
  const int tid = threadIdx.x;
  const int base = blockIdx.x*EBLK + tid*ECH;
  int cnt = 0;
  #pragma unroll
  for (int q = 0; q < ECH; ++q){
    int e = base + q;
    if (e < E){
      if (nmap[erow[e]] >= 0 && nmap[ecol[e]] >= 0) cnt++;
    }
  }
  sc[tid] = cnt; __syncthreads();
  for (int s = 128; s > 0; s >>= 1){
    if (tid < s) sc[tid] += sc[tid+s];
    __syncthreads();
  }
  if (tid == 0) bcount[blockIdx.x] = sc[0];
}

__global__ __launch_bounds__(1024) void k_escan(const int* __restrict__ bcount, int nblk,
                                                int* __restrict__ boff, int* __restrict__ tot){
  __shared__ int sh[1024];
  const int tid = threadIdx.x;
  int carry = 0;
  for (int s = 0; s < nblk; s += 1024){
    int v = (s + tid < nblk) ? bcount[s+tid] : 0;
    sh[tid] = v; __syncthreads();
    for (int d = 1; d < 1024; d <<= 1){
      int t = (tid >= d) ? sh[tid-d] : 0;
      __syncthreads();
      sh[tid] += t;
      __syncthreads();
    }
    if (s + tid < nblk) boff[s+tid] = carry + sh[tid] - v;
    carry += sh[1023];
    __syncthreads();
  }
  if (tid == 0) *tot = carry;
}

__global__ void k_efill_tail(float* __restrict__ outR, float* __restrict__ outC,
                             const int* __restrict__ tot, int E){
  const int t0 = *tot;
  int stride = gridDim.x*blockDim.x;
  for (int i = t0 + blockIdx.x*blockDim.x + threadIdx.x; i < E; i += stride){
    outR[i] = -1.0f;
    outC[i] = -1.0f;
  }
}

__global__ __launch_bounds__(256) void k_escatter(const int* __restrict__ erow, const int* __restrict__ ecol,
    const int* __restrict__ nmap, int E, const int* __restrict__ boff,
    float* __restrict__ outR, float* __restrict__ outC){
  __shared__ int sc[256];
  const int tid = threadIdx.x;
  const int base = blockIdx.x*EBLK + tid*ECH;
  int mr[ECH], mc[ECH];
  int cnt = 0;
  #pragma unroll
  for (int q = 0; q < ECH; ++q){
    int e = base + q;
    int a = -1, b = -1;
    if (e < E){ a = nmap[erow[e]]; b = nmap[ecol[e]]; }
    mr[q] = a; mc[q] = b;
    if (a >= 0 && b >= 0) cnt++;
  }
  sc[tid] = cnt; __syncthreads();
  int v = cnt;
  for (int d = 1; d < 256; d <<= 1){
    int t = (tid >= d) ? sc[tid-d] : 0;
    __syncthreads();
    sc[tid] += t;
    __syncthreads();
  }
  int pos = boff[blockIdx.x] + sc[tid] - v;
  #pragma unroll
  for (int q = 0; q < ECH; ++q){
    if (mr[q] >= 0 && mc[q] >= 0){
      outR[pos] = (float)mr[q];
      outC[pos] = (float)mc[q];
      pos++;
    }
  }
}

// ---------------- host ----------------
extern "C" void kernel_launch(void* const* d_in, const int* in_sizes, int n_in,
                              void* d_out, int out_size, void* d_ws, size_t ws_size,
                              hipStream_t stream)
{
  const float* x   = (const float*)d_in[0];
  const int*   ei  = (const int*)d_in[1];
  const float* wS1 = (const float*)d_in[2];
  const float* bS1 = (const float*)d_in[3];
  const float* wS2 = (const float*)d_in[4];
  const float* bS2 = (const float*)d_in[5];
  const float* wF1 = (const float*)d_in[6];
  const float* bF1 = (const float*)d_in[7];
  const float* wF2 = (const float*)d_in[8];
  const float* bF2 = (const float*)d_in[9];
  const float* wP  = (const float*)d_in[10];
  const float* bP  = (const float*)d_in[11];
  const float* alpha = (const float*)d_in[12];
  const float* beta  = (const float*)d_in[13];
  (void)n_in; (void)out_size; (void)ws_size;

  const int N = in_sizes[0] / D;
  const int E = in_sizes[1] / 2;
  int k = (int)(0.5 * (double)N); if (k < 1) k = 1;
  int SORTN = 8192; while (SORTN < N) SORTN <<= 1;   // 262144 for N=200000
  const int nblk_e = (E + EBLK - 1) / EBLK;

  char* w = (char*)d_ws;
  size_t off = 0;
  auto alloc = [&](size_t bytes)->char*{
    char* p = w + off;
    off = (off + bytes + 255) & ~(size_t)255;
    return p;
  };
  float*  s32    = (float*) alloc((size_t)N*4);
  u64*    keys   = (u64*)   alloc((size_t)SORTN*8);
  int*    deg    = (int*)   alloc((size_t)N*4);
  int*    nmap   = (int*)   alloc((size_t)N*4);
  double* s1b    = (double*)alloc((size_t)D*8);
  float*  s1bf   = (float*) alloc((size_t)D*4);
  double* scal   = (double*)alloc(4*8);
  float*  scalf  = (float*) alloc(4*4);
  u64*    sumsq  = (u64*)   alloc(8);
  float*  cutbuf = (float*) alloc(2*4);
  int*    r01    = (int*)   alloc(2*4);
  int*    tot    = (int*)   alloc(4);
  double* bandS  = (double*)alloc((size_t)2*BAND_W*8);
  u16*    wswH   = (u16*)   alloc((size_t)98304*2);
  u16*    wswL   = (u16*)   alloc((size_t)98304*2);
  u16*    wswPH  = (u16*)   alloc((size_t)65536*2);
  u16*    wswPL  = (u16*)   alloc((size_t)65536*2);
  int*    bcount = (int*)   alloc((size_t)nblk_e*4);
  int*    boff   = (int*)   alloc((size_t)nblk_e*4);

  float* outX  = (float*)d_out;
  float* outER = outX  + (size_t)k*D;
  float* outEC = outER + (size_t)E;
  float* outS  = outEC + (size_t)E;

  // deg8 replicas live in the (not-yet-written) outER region: 8*N*4 = 6.4 MB << E*4.
  // Fully consumed by k_degred before any edge-output kernel writes outER.
  u32* deg8 = (u32*)outER;

  hipMemsetAsync(deg8,  0,    (size_t)8*N*4, stream);
  hipMemsetAsync(sumsq, 0,    8,             stream);
  hipMemsetAsync(nmap,  0xFF, (size_t)N*4,   stream);   // = -1

  k_degree8<<<2048, 256, 0, stream>>>(ei, E, deg8, N);
  k_degred <<<1024, 256, 0, stream>>>(deg8, N, deg, sumsq);
  k_prep   <<<1,    D,   0, stream>>>(wS1, alpha, beta, sumsq, s1b, scal, s1bf, scalf);
  k_wsw    <<<384,  256, 0, stream>>>(wS1, wF1, wswH, wswL);
  k_wswP   <<<256,  256, 0, stream>>>(wP, wswPH, wswPL);
  k_scores_mfma<<<(N + 63)/64, 512, 0, stream>>>(x, deg, wswH, wswL,
                                                 bS1, wS2, bS2, bF1, wF2, bF2,
                                                 s1bf, scalf, s32, keys, N);
  k_padkeys<<<(SORTN - N + 255)/256, 256, 0, stream>>>(keys, N, SORTN);

  // sort packed keys ascending (= score desc, idx asc)
  k_bsort_local8k<<<SORTN/8192, 1024, 0, stream>>>(keys);
  for (int size = 16384; size <= SORTN; size <<= 1){
    int stride = size >> 1;
    while (stride >= 8192){
      int ns = 1;
      while (ns < 4 && (stride >> ns) >= 8192) ns++;
      switch (ns){
        case 1: k_bpassM<1><<<SORTN/2/256,  256, 0, stream>>>(keys, size, stride); break;
        case 2: k_bpassM<2><<<SORTN/4/256,  256, 0, stream>>>(keys, size, stride); break;
        case 3: k_bpassM<3><<<SORTN/8/256,  256, 0, stream>>>(keys, size, stride); break;
        default:k_bpassM<4><<<SORTN/16/256, 256, 0, stream>>>(keys, size, stride); break;
      }
      stride >>= ns;
    }
    k_bmerge_local8k<<<SORTN/8192, 1024, 0, stream>>>(keys, size);
  }

  // f64 band refinement around the cutoff
  kr_cut     <<<1, 64, 0, stream>>>(keys, k, cutbuf, r01);
  kr_rescore <<<2*BAND_W, 256, 0, stream>>>(keys, s32, x, deg, wS1,bS1,wS2,bS2,
                                            wF1,bF1,wF2,bF2, s1b, scal,
                                            cutbuf, r01, bandS, k, N);
  kr_bandsort<<<1, 1024, 0, stream>>>(keys, bandS, r01, k);

  k_finalize<<<(k+255)/256, 256, 0, stream>>>(keys, s32, k, nmap, outS);
  k_xpool_mfma<<<(k+63)/64, 512, 0, stream>>>(x, keys, wswPH, wswPL, bP, outX, k);
  k_ecount  <<<nblk_e, 256, 0, stream>>>(ei, ei+E, nmap, E, bcount);
  k_escan   <<<1, 1024, 0, stream>>>(bcount, nblk_e, boff, tot);
  k_efill_tail<<<1024, 256, 0, stream>>>(outER, outEC, tot, E);
  k_escatter<<<nblk_e, 256, 0, stream>>>(ei, ei+E, nmap, E, boff, outER, outEC);
}

// Round 6
// 828.763 us; speedup vs baseline: 4.3097x; 1.1820x over previous
//
#include <hip/hip_runtime.h>
#include <math.h>

typedef unsigned long long u64;
typedef unsigned int u32;
typedef unsigned short u16;
typedef __attribute__((ext_vector_type(8))) short bf16x8;
typedef __attribute__((ext_vector_type(4))) float f32x4;

#define D   256
#define ECH 16          // edges per thread
#define EBLK (256*ECH)  // edges per block
#define BAND_W 4096     // rank window half-width around k for f64 refinement
#define BAND_DELTA 1e-3f
#define HR  12544       // histogram nodes per range (50 KB LDS)
#define HCH 32          // edge chunks (blocks per range)

__device__ __forceinline__ double lrelu(double v){ return v > 0.0 ? v : 0.2*v; }
__device__ __forceinline__ float  lreluf(float v){ return v > 0.0f ? v : 0.2f*v; }

__device__ __forceinline__ u16 f2bf(float f){
  union{float f; u32 u;} v; v.f = f;
  u32 r = v.u + 0x7FFFu + ((v.u >> 16) & 1u);   // RNE
  return (u16)(r >> 16);
}
__device__ __forceinline__ float bf2f(u16 b){
  union{u32 u; float f;} v; v.u = ((u32)b) << 16; return v.f;
}

// ---------------- degree: partitioned LDS histogram (no global atomics) -------------
// Block (r = blockIdx % NR, c = blockIdx / NR): stream edge chunk c, count rows in
// range [r*HR, r*HR+HR) in LDS, write partial plane. Exact integer sums -> deterministic.
__global__ __launch_bounds__(256) void k_deghist(const int* __restrict__ row, int E,
                                                 u32* __restrict__ partial, int NR){
  __shared__ u32 h[HR];
  const int tid = threadIdx.x;
  const int r = blockIdx.x % NR;
  const int c = blockIdx.x / NR;
  for (int i = tid; i < HR; i += 256) h[i] = 0;
  __syncthreads();
  const int lo = r * HR;
  int CE = ((E + HCH - 1) / HCH + 3) & ~3;      // chunk size, multiple of 4
  const int e0 = c * CE;
  const int e1 = min(e0 + CE, E);
  for (int e = e0 + tid*4; e < e1; e += 256*4){
    if (e + 3 < e1){
      int4 v = *(const int4*)(row + e);
      u32 d0 = (u32)(v.x - lo), d1 = (u32)(v.y - lo);
      u32 d2 = (u32)(v.z - lo), d3 = (u32)(v.w - lo);
      if (d0 < (u32)HR) atomicAdd(&h[d0], 1u);
      if (d1 < (u32)HR) atomicAdd(&h[d1], 1u);
      if (d2 < (u32)HR) atomicAdd(&h[d2], 1u);
      if (d3 < (u32)HR) atomicAdd(&h[d3], 1u);
    } else {
      for (int j = 0; j < 4 && e + j < e1; ++j){
        u32 d = (u32)(row[e+j] - lo);
        if (d < (u32)HR) atomicAdd(&h[d], 1u);
      }
    }
  }
  __syncthreads();
  u32* plane = partial + (size_t)blockIdx.x * HR;
  for (int i = tid; i < HR; i += 256) plane[i] = h[i];
}

// reduce partial planes + fused deg^2 sum. plane for (r,c) = c*NR + r.
__global__ void k_degred2(const u32* __restrict__ partial, int N, int NR,
                          int* __restrict__ deg, u64* __restrict__ out){
  __shared__ u64 sh[256];
  u64 local = 0;
  int stride = gridDim.x*blockDim.x;
  for (int i = blockIdx.x*blockDim.x + threadIdx.x; i < N; i += stride){
    int r = i / HR, off = i % HR;
    u32 s = 0;
    #pragma unroll 8
    for (int c = 0; c < HCH; ++c) s += partial[(size_t)(c*NR + r)*HR + off];
    deg[i] = (int)s;
    local += (u64)s * (u64)s;
  }
  sh[threadIdx.x] = local; __syncthreads();
  for (int s = 128; s > 0; s >>= 1){
    if (threadIdx.x < s) sh[threadIdx.x] += sh[threadIdx.x+s];
    __syncthreads();
  }
  if (threadIdx.x == 0) atomicAdd(out, sh[0]);
}

// s1b[j] = sum_{r=256..511} w_s1[r][j]; plus scalar weights (f64 + f32 copies)
__global__ void k_prep(const float* __restrict__ wS1, const float* __restrict__ alpha,
                       const float* __restrict__ beta, const u64* __restrict__ sumsq,
                       double* __restrict__ s1b, double* __restrict__ scal,
                       float* __restrict__ s1bf, float* __restrict__ scalf){
  int j = threadIdx.x;
  double s = 0.0;
  for (int r = 0; r < D; ++r) s += (double)wS1[(D + r)*D + j];
  s1b[j] = s;
  s1bf[j] = (float)s;
  if (j == 0){
    double a = 1.0/(1.0 + exp(-(double)alpha[0]));
    double b = 1.0/(1.0 + exp(-(double)beta[0]));
    scal[0] = a/(a+b);
    scal[1] = b/(a+b);
    double dn = sqrt((double)(*sumsq));
    scal[2] = dn > 1e-12 ? dn : 1e-12;
    scalf[0] = (float)scal[0];
    scalf[1] = (float)scal[1];
    scalf[2] = (float)(1.0/scal[2]);
  }
}

// ---------------- weight pre-swizzle into MFMA B-fragment order (hi/lo bf16) ---------
__global__ void k_wsw(const float* __restrict__ wS1, const float* __restrict__ wF1,
                      u16* __restrict__ wswH, u16* __restrict__ wswL){
  int idx = blockIdx.x*blockDim.x + threadIdx.x;   // 24*8*64*8 = 98304
  int i    = idx & 7;
  int lane = (idx >> 3) & 63;
  int sg   = (idx >> 9) & 7;
  int t    = idx >> 12;
  int k = sg*32 + ((lane >> 4) & 3)*8 + i;
  int c16 = lane & 15;
  float wv;
  if (t < 16) wv = wS1[k*256 + t*16 + c16];
  else        wv = wF1[k*128 + (t-16)*16 + c16];
  u16 h = f2bf(wv);
  float lo = wv - bf2f(h);
  wswH[idx] = h;
  wswL[idx] = f2bf(lo);
}

__global__ void k_wswP(const float* __restrict__ wP,
                       u16* __restrict__ wH, u16* __restrict__ wL){
  int idx = blockIdx.x*blockDim.x + threadIdx.x;   // 16*8*64*8 = 65536
  int i    = idx & 7;
  int lane = (idx >> 3) & 63;
  int sg   = (idx >> 9) & 7;
  int t    = idx >> 12;
  int k = sg*32 + ((lane >> 4) & 3)*8 + i;
  float wv = wP[k*256 + t*16 + (lane & 15)];
  u16 h = f2bf(wv);
  float lo = wv - bf2f(h);
  wH[idx] = h;
  wL[idx] = f2bf(lo);
}

// ---------------- scores via split-bf16 MFMA ----------------
__global__ __launch_bounds__(512, 4) void k_scores_mfma(
    const float* __restrict__ x, const int* __restrict__ deg,
    const u16* __restrict__ wswH, const u16* __restrict__ wswL,
    const float* __restrict__ bS1, const float* __restrict__ wS2, const float* __restrict__ bS2,
    const float* __restrict__ bF1, const float* __restrict__ wF2, const float* __restrict__ bF2,
    const float* __restrict__ s1bf, const float* __restrict__ scalf,
    float* __restrict__ s32, u64* __restrict__ keys, int N)
{
  __shared__ u16 xsh[2][4096];     // [buf][row*8 + swz(seg)] 16B units of 8 bf16
  __shared__ u16 xsl[2][4096];
  __shared__ float dnsh[64];
  __shared__ float part_s[64][9];
  __shared__ float part_f[64][9];

  const int tid  = threadIdx.x;
  const int lane = tid & 63;
  const int w    = tid >> 6;
  const int node0 = blockIdx.x * 64;

  if (tid < 64){
    int node = node0 + tid;
    dnsh[tid] = (node < N) ? ((float)deg[node] * scalf[2]) : 0.0f;
  }

  const int row_st = tid >> 3;          // 0..63
  const int seg_st = tid & 7;           // 0..7 (8 bf16 per seg)
  const int unit_w = row_st*8 + (seg_st ^ (row_st & 7));
  const float* srcbase = x + (size_t)(node0 + row_st)*D + seg_st*8;
  const bool rv = (node0 + row_st) < N;

  f32x4 acc[4][3];
  #pragma unroll
  for (int m = 0; m < 4; ++m)
    #pragma unroll
    for (int n = 0; n < 3; ++n) acc[m][n] = (f32x4){0.f,0.f,0.f,0.f};

  float xr[8];
  {
    if (rv){
      float4 a = *(const float4*)(srcbase);
      float4 b = *(const float4*)(srcbase + 4);
      xr[0]=a.x; xr[1]=a.y; xr[2]=a.z; xr[3]=a.w;
      xr[4]=b.x; xr[5]=b.y; xr[6]=b.z; xr[7]=b.w;
    } else {
      #pragma unroll
      for (int i = 0; i < 8; ++i) xr[i] = 0.f;
    }
  }

  #pragma unroll
  for (int c = 0; c < 4; ++c){
    const int pb = c & 1;
    {
      u16 h[8];
      #pragma unroll
      for (int i = 0; i < 8; ++i) h[i] = f2bf(xr[i]);
      uint4 H; H.x = (u32)h[0] | ((u32)h[1]<<16); H.y = (u32)h[2] | ((u32)h[3]<<16);
               H.z = (u32)h[4] | ((u32)h[5]<<16); H.w = (u32)h[6] | ((u32)h[7]<<16);
      u16 l[8];
      #pragma unroll
      for (int i = 0; i < 8; ++i) l[i] = f2bf(xr[i] - bf2f(h[i]));
      uint4 L; L.x = (u32)l[0] | ((u32)l[1]<<16); L.y = (u32)l[2] | ((u32)l[3]<<16);
               L.z = (u32)l[4] | ((u32)l[5]<<16); L.w = (u32)l[6] | ((u32)l[7]<<16);
      *(uint4*)&xsh[pb][unit_w*8] = H;
      *(uint4*)&xsl[pb][unit_w*8] = L;
    }
    if (c < 3){
      const float* sn = srcbase + (c+1)*64;
      if (rv){
        float4 a = *(const float4*)(sn);
        float4 b = *(const float4*)(sn + 4);
        xr[0]=a.x; xr[1]=a.y; xr[2]=a.z; xr[3]=a.w;
        xr[4]=b.x; xr[5]=b.y; xr[6]=b.z; xr[7]=b.w;
      }
    }
    __syncthreads();
    #pragma unroll
    for (int s = 0; s < 2; ++s){
      const int sg = c*2 + s;
      bf16x8 ah[4], al[4];
      #pragma unroll
      for (int mt = 0; mt < 4; ++mt){
        int row = mt*16 + (lane & 15);
        int seg = s*4 + (lane >> 4);
        int un  = row*8 + (seg ^ (row & 7));
        ah[mt] = *(const bf16x8*)&xsh[pb][un*8];
        al[mt] = *(const bf16x8*)&xsl[pb][un*8];
      }
      const int t0 = w*3;
      size_t o0 = ((size_t)(t0*8 + sg)*64 + lane)*8;
      bf16x8 bh = *(const bf16x8*)&wswH[o0];
      bf16x8 bl = *(const bf16x8*)&wswL[o0];
      #pragma unroll
      for (int nt = 0; nt < 3; ++nt){
        bf16x8 nbh = bh, nbl = bl;
        if (nt < 2){
          size_t on = ((size_t)((t0+nt+1)*8 + sg)*64 + lane)*8;
          nbh = *(const bf16x8*)&wswH[on];
          nbl = *(const bf16x8*)&wswL[on];
        }
        #pragma unroll
        for (int mt = 0; mt < 4; ++mt){
          acc[mt][nt] = __builtin_amdgcn_mfma_f32_16x16x32_bf16(ah[mt], bh, acc[mt][nt], 0,0,0);
          acc[mt][nt] = __builtin_amdgcn_mfma_f32_16x16x32_bf16(al[mt], bh, acc[mt][nt], 0,0,0);
          acc[mt][nt] = __builtin_amdgcn_mfma_f32_16x16x32_bf16(ah[mt], bl, acc[mt][nt], 0,0,0);
        }
        bh = nbh; bl = nbl;
      }
    }
    __syncthreads();
  }

  // epilogue: per-wave activation + column reduction
  float dnl[4][4];
  #pragma unroll
  for (int mt = 0; mt < 4; ++mt)
    #pragma unroll
    for (int j = 0; j < 4; ++j)
      dnl[mt][j] = dnsh[mt*16 + (lane>>4)*4 + j];

  float ps[4][4], pf[4][4];
  #pragma unroll
  for (int mt = 0; mt < 4; ++mt)
    #pragma unroll
    for (int j = 0; j < 4; ++j){ ps[mt][j] = 0.f; pf[mt][j] = 0.f; }

  #pragma unroll
  for (int nt = 0; nt < 3; ++nt){
    const int t = w*3 + nt;
    const int c16 = lane & 15;
    const bool isS = (t < 16);
    const int col = isS ? t*16 + c16 : (t-16)*16 + c16;
    const float bias = isS ? bS1[col] : bF1[col];
    const float sbv  = isS ? s1bf[col] : 0.f;
    const float vv   = isS ? wS2[col] : wF2[col];
    #pragma unroll
    for (int mt = 0; mt < 4; ++mt){
      #pragma unroll
      for (int j = 0; j < 4; ++j){
        float v = acc[mt][nt][j] + bias + dnl[mt][j]*sbv;
        v = lreluf(v) * vv;
        v += __shfl_xor(v, 1);
        v += __shfl_xor(v, 2);
        v += __shfl_xor(v, 4);
        v += __shfl_xor(v, 8);
        if (isS) ps[mt][j] += v; else pf[mt][j] += v;
      }
    }
  }
  if ((lane & 15) == 0){
    #pragma unroll
    for (int mt = 0; mt < 4; ++mt)
      #pragma unroll
      for (int j = 0; j < 4; ++j){
        int row = mt*16 + (lane>>4)*4 + j;
        part_s[row][w] = ps[mt][j];
        part_f[row][w] = pf[mt][j];
      }
  }
  __syncthreads();
  if (tid < 64){
    int node = node0 + tid;
    if (node < N){
      float sv = 0.f, fv = 0.f;
      #pragma unroll
      for (int ww = 0; ww < 8; ++ww){ sv += part_s[tid][ww]; fv += part_f[tid][ww]; }
      float sc = scalf[0]*(sv + bS2[0]) + scalf[1]*(fv + bF2[0]);
      s32[node] = sc;
      u32 bits = __float_as_uint(sc);
      u32 ord = (bits >> 31) ? ~bits : (bits | 0x80000000u);
      keys[node] = ((u64)(~ord) << 32) | (u32)node;
    }
  }
}

__global__ void k_padkeys(u64* __restrict__ keys, int N, int SORTN){
  int i = N + blockIdx.x*blockDim.x + threadIdx.x;
  if (i < SORTN) keys[i] = ~0ULL;
}

// ---------------- bitonic sort on packed u64 ----------------
__global__ __launch_bounds__(1024) void k_bsort_local8k(u64* __restrict__ keys){
  __shared__ u64 sk[8192];
  const int tid = threadIdx.x;
  const int base = blockIdx.x * 8192;
  #pragma unroll
  for (int e = 0; e < 8; ++e) sk[tid + e*1024] = keys[base + tid + e*1024];
  __syncthreads();
  for (int size = 2; size <= 8192; size <<= 1){
    for (int stride = size >> 1; stride > 0; stride >>= 1){
      #pragma unroll
      for (int pp = 0; pp < 4; ++pp){
        int p  = tid + pp*1024;
        int i  = 2*p - (p & (stride-1));
        int jj = i + stride;
        bool up = (((base + i) & size) == 0);
        u64 ki = sk[i], kj = sk[jj];
        if ((ki > kj) == up){ sk[i] = kj; sk[jj] = ki; }
      }
      __syncthreads();
    }
  }
  #pragma unroll
  for (int e = 0; e < 8; ++e) keys[base + tid + e*1024] = sk[tid + e*1024];
}

__global__ __launch_bounds__(1024) void k_bmerge_local8k(u64* __restrict__ keys, int size){
  __shared__ u64 sk[8192];
  const int tid = threadIdx.x;
  const int base = blockIdx.x * 8192;
  #pragma unroll
  for (int e = 0; e < 8; ++e) sk[tid + e*1024] = keys[base + tid + e*1024];
  __syncthreads();
  for (int stride = 4096; stride > 0; stride >>= 1){
    #pragma unroll
    for (int pp = 0; pp < 4; ++pp){
      int p  = tid + pp*1024;
      int i  = 2*p - (p & (stride-1));
      int jj = i + stride;
      bool up = (((base + i) & size) == 0);
      u64 ki = sk[i], kj = sk[jj];
      if ((ki > kj) == up){ sk[i] = kj; sk[jj] = ki; }
    }
    __syncthreads();
  }
  #pragma unroll
  for (int e = 0; e < 8; ++e) keys[base + tid + e*1024] = sk[tid + e*1024];
}

template<int NS>
__global__ void k_bpassM(u64* __restrict__ keys, int size, int stride){
  const int G = 1 << NS;
  u32 t = blockIdx.x*blockDim.x + threadIdx.x;
  u32 smin = (u32)stride >> (NS-1);
  u32 i0 = (t/smin)*(smin << NS) + (t % smin);
  u64 v[G];
  #pragma unroll
  for (int j = 0; j < G; ++j) v[j] = keys[i0 + (u32)j*smin];
  bool up = ((i0 & (u32)size) == 0);
  #pragma unroll
  for (int b = (G>>1); b >= 1; b >>= 1){
    #pragma unroll
    for (int j = 0; j < G; ++j){
      if ((j & b) == 0){
        u64 a = v[j], cc = v[j|b];
        if ((a > cc) == up){ v[j] = cc; v[j|b] = a; }
      }
    }
  }
  #pragma unroll
  for (int j = 0; j < G; ++j) keys[i0 + (u32)j*smin] = v[j];
}

// ---------------- f64 band refinement around rank-k cutoff ----------------
__global__ void kr_cut(const u64* __restrict__ keys, int k, float* __restrict__ cutbuf,
                       int* __restrict__ r01){
  if (threadIdx.x == 0 && blockIdx.x == 0){
    u32 key32 = (u32)(keys[k-1] >> 32);
    u32 ord = ~key32;
    u32 u = (ord & 0x80000000u) ? (ord ^ 0x80000000u) : ~ord;
    float c = __uint_as_float(u);
    cutbuf[0] = c - BAND_DELTA;
    cutbuf[1] = c + BAND_DELTA;
    r01[0] = 0x7FFFFFFF;
    r01[1] = -1;
  }
}

__global__ __launch_bounds__(256) void kr_rescore(
    const u64* __restrict__ keys, const float* __restrict__ s32,
    const float* __restrict__ x, const int* __restrict__ deg,
    const float* __restrict__ wS1, const float* __restrict__ bS1,
    const float* __restrict__ wS2, const float* __restrict__ bS2,
    const float* __restrict__ wF1, const float* __restrict__ bF1,
    const float* __restrict__ wF2, const float* __restrict__ bF2,
    const double* __restrict__ s1b, const double* __restrict__ scal,
    const float* __restrict__ cutbuf, int* __restrict__ r01,
    double* __restrict__ bandS, int k, int N)
{
  const int r = k - BAND_W + blockIdx.x;
  if (r < 0 || r >= N) return;
  const int node = (int)(u32)(keys[r] & 0xFFFFFFFFULL);
  const float s = s32[node];
  if (s < cutbuf[0] || s > cutbuf[1]) return;

  const int tid = threadIdx.x;
  if (tid == 0){ atomicMin(&r01[0], r); atomicMax(&r01[1], r); }

  __shared__ float xr[256];
  __shared__ double rsp[4], rfp[4];
  xr[tid] = x[(size_t)node*D + tid];
  __syncthreads();

  const int j = tid;
  double accA = (double)bS1[j] + ((double)deg[node]/scal[2]) * s1b[j];
  double accB = (j < 128) ? (double)bF1[j] : 0.0;
  for (int rr = 0; rr < D; ++rr){
    double xv = (double)xr[rr];
    accA = fma(xv, (double)wS1[rr*D + j], accA);
    if (j < 128) accB = fma(xv, (double)wF1[rr*128 + j], accB);
  }
  double sp = lrelu(accA) * (double)wS2[j];
  double fp = (j < 128) ? lrelu(accB) * (double)wF2[j] : 0.0;

  const int lane = tid & 63, wave = tid >> 6;
  #pragma unroll
  for (int off = 32; off > 0; off >>= 1){
    sp += __shfl_down(sp, off);
    fp += __shfl_down(fp, off);
  }
  if (lane == 0){ rsp[wave] = sp; rfp[wave] = fp; }
  __syncthreads();
  if (tid == 0){
    double SP = rsp[0]+rsp[1]+rsp[2]+rsp[3];
    double FP = rfp[0]+rfp[1]+rfp[2]+rfp[3];
    bandS[blockIdx.x] = scal[0]*(SP + (double)bS2[0]) + scal[1]*(FP + (double)bF2[0]);
  }
}

__global__ __launch_bounds__(1024) void kr_bandsort(u64* __restrict__ keys,
    const double* __restrict__ bandS, const int* __restrict__ r01, int k){
  __shared__ double bs[8192];
  __shared__ int bi[8192];
  const int r0 = r01[0], r1 = r01[1];
  int nb = r1 - r0 + 1;
  if (nb <= 1) return;
  if (nb > 8192) nb = 8192;
  int M = 1; while (M < nb) M <<= 1;
  const int tid = threadIdx.x;
  const int sbase = r0 - (k - BAND_W);
  for (int m = tid; m < M; m += 1024){
    if (m < nb){ bs[m] = bandS[sbase + m]; bi[m] = (int)(u32)(keys[r0+m] & 0xFFFFFFFFULL); }
    else       { bs[m] = -1.0/0.0;         bi[m] = 0x7FFFFFFF; }
  }
  __syncthreads();
  for (int size = 2; size <= M; size <<= 1){
    for (int stride = size >> 1; stride > 0; stride >>= 1){
      for (int p = tid; p < (M >> 1); p += 1024){
        int i = 2*p - (p & (stride-1));
        int jj = i + stride;
        bool up = ((i & size) == 0);
        double si_ = bs[i], sj = bs[jj];
        int ii = bi[i], ij = bi[jj];
        bool gt = (si_ < sj) || (si_ == sj && ii > ij);
        if (gt == up){ bs[i]=sj; bs[jj]=si_; bi[i]=ij; bi[jj]=ii; }
      }
      __syncthreads();
    }
  }
  for (int m = tid; m < nb; m += 1024)
    keys[r0+m] = (u64)(u32)bi[m];
}

// ---------------- post-topk: node_map + topk_scores fused ----------------
__global__ void k_finalize(const u64* __restrict__ keys, const float* __restrict__ s32,
                           int k, int* __restrict__ nmap, float* __restrict__ outS){
  int p = blockIdx.x*blockDim.x + threadIdx.x;
  if (p < k){
    int node = (int)(u32)(keys[p] & 0xFFFFFFFFULL);
    nmap[node] = p;
    outS[p] = s32[node];
  }
}

// ---------------- x_pooled via split-bf16 MFMA ----------------
__global__ __launch_bounds__(512, 4) void k_xpool_mfma(
    const float* __restrict__ x, const u64* __restrict__ keys,
    const u16* __restrict__ wH, const u16* __restrict__ wL,
    const float* __restrict__ bP, float* __restrict__ out, int kk)
{
  __shared__ u16 xsh[2][4096];
  __shared__ u16 xsl[2][4096];

  const int tid  = threadIdx.x;
  const int lane = tid & 63;
  const int w    = tid >> 6;
  const int p0 = blockIdx.x * 64;
  if (p0 >= kk) return;

  const int row_st = tid >> 3;
  const int seg_st = tid & 7;
  const int unit_w = row_st*8 + (seg_st ^ (row_st & 7));
  int prow = p0 + row_st; if (prow >= kk) prow = kk - 1;
  const int node = (int)(u32)(keys[prow] & 0xFFFFFFFFULL);
  const float* srcbase = x + (size_t)node*D + seg_st*8;

  f32x4 acc[4][2];
  #pragma unroll
  for (int m = 0; m < 4; ++m){ acc[m][0] = (f32x4){0.f,0.f,0.f,0.f}; acc[m][1] = (f32x4){0.f,0.f,0.f,0.f}; }

  float xr[8];
  {
    float4 a = *(const float4*)(srcbase);
    float4 b = *(const float4*)(srcbase + 4);
    xr[0]=a.x; xr[1]=a.y; xr[2]=a.z; xr[3]=a.w;
    xr[4]=b.x; xr[5]=b.y; xr[6]=b.z; xr[7]=b.w;
  }

  #pragma unroll
  for (int c = 0; c < 4; ++c){
    const int pb = c & 1;
    {
      u16 h[8];
      #pragma unroll
      for (int i = 0; i < 8; ++i) h[i] = f2bf(xr[i]);
      uint4 H; H.x = (u32)h[0] | ((u32)h[1]<<16); H.y = (u32)h[2] | ((u32)h[3]<<16);
               H.z = (u32)h[4] | ((u32)h[5]<<16); H.w = (u32)h[6] | ((u32)h[7]<<16);
      u16 l[8];
      #pragma unroll
      for (int i = 0; i < 8; ++i) l[i] = f2bf(xr[i] - bf2f(h[i]));
      uint4 L; L.x = (u32)l[0] | ((u32)l[1]<<16); L.y = (u32)l[2] | ((u32)l[3]<<16);
               L.z = (u32)l[4] | ((u32)l[5]<<16); L.w = (u32)l[6] | ((u32)l[7]<<16);
      *(uint4*)&xsh[pb][unit_w*8] = H;
      *(uint4*)&xsl[pb][unit_w*8] = L;
    }
    if (c < 3){
      const float* sn = srcbase + (c+1)*64;
      float4 a = *(const float4*)(sn);
      float4 b = *(const float4*)(sn + 4);
      xr[0]=a.x; xr[1]=a.y; xr[2]=a.z; xr[3]=a.w;
      xr[4]=b.x; xr[5]=b.y; xr[6]=b.z; xr[7]=b.w;
    }
    __syncthreads();
    #pragma unroll
    for (int s = 0; s < 2; ++s){
      const int sg = c*2 + s;
      bf16x8 ah[4], al[4];
      #pragma unroll
      for (int mt = 0; mt < 4; ++mt){
        int row = mt*16 + (lane & 15);
        int seg = s*4 + (lane >> 4);
        int un  = row*8 + (seg ^ (row & 7));
        ah[mt] = *(const bf16x8*)&xsh[pb][un*8];
        al[mt] = *(const bf16x8*)&xsl[pb][un*8];
      }
      const int t0 = w*2;
      size_t o0 = ((size_t)(t0*8 + sg)*64 + lane)*8;
      bf16x8 bh = *(const bf16x8*)&wH[o0];
      bf16x8 bl = *(const bf16x8*)&wL[o0];
      #pragma unroll
      for (int nt = 0; nt < 2; ++nt){
        bf16x8 nbh = bh, nbl = bl;
        if (nt < 1){
          size_t on = ((size_t)((t0+1)*8 + sg)*64 + lane)*8;
          nbh = *(const bf16x8*)&wH[on];
          nbl = *(const bf16x8*)&wL[on];
        }
        #pragma unroll
        for (int mt = 0; mt < 4; ++mt){
          acc[mt][nt] = __builtin_amdgcn_mfma_f32_16x16x32_bf16(ah[mt], bh, acc[mt][nt], 0,0,0);
          acc[mt][nt] = __builtin_amdgcn_mfma_f32_16x16x32_bf16(al[mt], bh, acc[mt][nt], 0,0,0);
          acc[mt][nt] = __builtin_amdgcn_mfma_f32_16x16x32_bf16(ah[mt], bl, acc[mt][nt], 0,0,0);
        }
        bh = nbh; bl = nbl;
      }
    }
    __syncthreads();
  }

  const int c16 = lane & 15, r4 = (lane >> 4)*4;
  #pragma unroll
  for (int nt = 0; nt < 2; ++nt){
    const int col = (w*2 + nt)*16 + c16;
    const float bias = bP[col];
    #pragma unroll
    for (int mt = 0; mt < 4; ++mt){
      #pragma unroll
      for (int j = 0; j < 4; ++j){
        int p = p0 + mt*16 + r4 + j;
        if (p < kk) out[(size_t)p*D + col] = lreluf(acc[mt][nt][j] + bias);
      }
    }
  }
}

// ---------------- edge remap + stable compaction ----------------
__global__ __launch_bounds__(256) void k_ecount(const int* __restrict__ erow, const int* __restrict__ ecol,
    const int* __restrict__ nmap, int E, int* __restrict__ bcount){
  __shared__ int sc[256];
  const int tid = threadIdx.x;
  const int base = blockIdx.x*EBLK + tid*ECH;
  int cnt = 0;
  #pragma unroll
  for (int q = 0; q < ECH; ++q){
    int e = base + q;
    if (e < E){
      if (nmap[erow[e]] >= 0 && nmap[ecol[e]] >= 0) cnt++;
    }
  }
  sc[tid] = cnt; __syncthreads();
  for (int s = 128; s > 0; s >>= 1){
    if (tid < s) sc[tid] += sc[tid+s];
    __syncthreads();
  }
  if (tid == 0) bcount[blockIdx.x] = sc[0];
}

__global__ __launch_bounds__(1024) void k_escan(const int* __restrict__ bcount, int nblk,
                                                int* __restrict__ boff, int* __restrict__ tot){
  __shared__ int sh[1024];
  const int tid = threadIdx.x;
  int carry = 0;
  for (int s = 0; s < nblk; s += 1024){
    int v = (s + tid < nblk) ? bcount[s+tid] : 0;
    sh[tid] = v; __syncthreads();
    for (int d = 1; d < 1024; d <<= 1){
      int t = (tid >= d) ? sh[tid-d] : 0;
      __syncthreads();
      sh[tid] += t;
      __syncthreads();
    }
    if (s + tid < nblk) boff[s+tid] = carry + sh[tid] - v;
    carry += sh[1023];
    __syncthreads();
  }
  if (tid == 0) *tot = carry;
}

__global__ void k_efill_tail(float* __restrict__ outR, float* __restrict__ outC,
                             const int* __restrict__ tot, int E){
  const int t0 = *tot;
  int stride = gridDim.x*blockDim.x;
  for (int i = t0 + blockIdx.x*blockDim.x + threadIdx.x; i < E; i += stride){
    outR[i] = -1.0f;
    outC[i] = -1.0f;
  }
}

__global__ __launch_bounds__(256) void k_escatter(const int* __restrict__ erow, const int* __restrict__ ecol,
    const int* __restrict__ nmap, int E, const int* __restrict__ boff,
    float* __restrict__ outR, float* __restrict__ outC){
  __shared__ int sc[256];
  const int tid = threadIdx.x;
  const int base = blockIdx.x*EBLK + tid*ECH;
  int mr[ECH], mc[ECH];
  int cnt = 0;
  #pragma unroll
  for (int q = 0; q < ECH; ++q){
    int e = base + q;
    int a = -1, b = -1;
    if (e < E){ a = nmap[erow[e]]; b = nmap[ecol[e]]; }
    mr[q] = a; mc[q] = b;
    if (a >= 0 && b >= 0) cnt++;
  }
  sc[tid] = cnt; __syncthreads();
  int v = cnt;
  for (int d = 1; d < 256; d <<= 1){
    int t = (tid >= d) ? sc[tid-d] : 0;
    __syncthreads();
    sc[tid] += t;
    __syncthreads();
  }
  int pos = boff[blockIdx.x] + sc[tid] - v;
  #pragma unroll
  for (int q = 0; q < ECH; ++q){
    if (mr[q] >= 0 && mc[q] >= 0){
      outR[pos] = (float)mr[q];
      outC[pos] = (float)mc[q];
      pos++;
    }
  }
}

// ---------------- host ----------------
extern "C" void kernel_launch(void* const* d_in, const int* in_sizes, int n_in,
                              void* d_out, int out_size, void* d_ws, size_t ws_size,
                              hipStream_t stream)
{
  const float* x   = (const float*)d_in[0];
  const int*   ei  = (const int*)d_in[1];
  const float* wS1 = (const float*)d_in[2];
  const float* bS1 = (const float*)d_in[3];
  const float* wS2 = (const float*)d_in[4];
  const float* bS2 = (const float*)d_in[5];
  const float* wF1 = (const float*)d_in[6];
  const float* bF1 = (const float*)d_in[7];
  const float* wF2 = (const float*)d_in[8];
  const float* bF2 = (const float*)d_in[9];
  const float* wP  = (const float*)d_in[10];
  const float* bP  = (const float*)d_in[11];
  const float* alpha = (const float*)d_in[12];
  const float* beta  = (const float*)d_in[13];
  (void)n_in; (void)out_size; (void)ws_size;

  const int N = in_sizes[0] / D;
  const int E = in_sizes[1] / 2;
  int k = (int)(0.5 * (double)N); if (k < 1) k = 1;
  int SORTN = 8192; while (SORTN < N) SORTN <<= 1;   // 262144 for N=200000
  const int nblk_e = (E + EBLK - 1) / EBLK;
  const int NR = (N + HR - 1) / HR;                  // histogram ranges (16 @ N=200k)

  char* w = (char*)d_ws;
  size_t off = 0;
  auto alloc = [&](size_t bytes)->char*{
    char* p = w + off;
    off = (off + bytes + 255) & ~(size_t)255;
    return p;
  };
  float*  s32    = (float*) alloc((size_t)N*4);
  u64*    keys   = (u64*)   alloc((size_t)SORTN*8);
  int*    deg    = (int*)   alloc((size_t)N*4);
  int*    nmap   = (int*)   alloc((size_t)N*4);
  double* s1b    = (double*)alloc((size_t)D*8);
  float*  s1bf   = (float*) alloc((size_t)D*4);
  double* scal   = (double*)alloc(4*8);
  float*  scalf  = (float*) alloc(4*4);
  u64*    sumsq  = (u64*)   alloc(8);
  float*  cutbuf = (float*) alloc(2*4);
  int*    r01    = (int*)   alloc(2*4);
  int*    tot    = (int*)   alloc(4);
  double* bandS  = (double*)alloc((size_t)2*BAND_W*8);
  u16*    wswH   = (u16*)   alloc((size_t)98304*2);
  u16*    wswL   = (u16*)   alloc((size_t)98304*2);
  u16*    wswPH  = (u16*)   alloc((size_t)65536*2);
  u16*    wswPL  = (u16*)   alloc((size_t)65536*2);
  int*    bcount = (int*)   alloc((size_t)nblk_e*4);
  int*    boff   = (int*)   alloc((size_t)nblk_e*4);

  float* outX  = (float*)d_out;
  float* outER = outX  + (size_t)k*D;
  float* outEC = outER + (size_t)E;
  float* outS  = outEC + (size_t)E;

  // degree histogram partials live in the (not-yet-written) outER/outEC region:
  // NR*HCH*HR*4 = 25.7 MB << 2*E*4 = 51.2 MB. Fully consumed by k_degred2 before
  // any edge-output kernel writes this region. No memset needed (planes fully written).
  u32* partial = (u32*)outER;

  hipMemsetAsync(sumsq, 0,    8,           stream);
  hipMemsetAsync(nmap,  0xFF, (size_t)N*4, stream);   // = -1

  k_deghist<<<NR*HCH, 256, 0, stream>>>(ei, E, partial, NR);
  k_degred2<<<1024, 256, 0, stream>>>(partial, N, NR, deg, sumsq);
  k_prep   <<<1,    D,   0, stream>>>(wS1, alpha, beta, sumsq, s1b, scal, s1bf, scalf);
  k_wsw    <<<384,  256, 0, stream>>>(wS1, wF1, wswH, wswL);
  k_wswP   <<<256,  256, 0, stream>>>(wP, wswPH, wswPL);
  k_scores_mfma<<<(N + 63)/64, 512, 0, stream>>>(x, deg, wswH, wswL,
                                                 bS1, wS2, bS2, bF1, wF2, bF2,
                                                 s1bf, scalf, s32, keys, N);
  k_padkeys<<<(SORTN - N + 255)/256, 256, 0, stream>>>(keys, N, SORTN);

  // sort packed keys ascending (= score desc, idx asc)
  k_bsort_local8k<<<SORTN/8192, 1024, 0, stream>>>(keys);
  for (int size = 16384; size <= SORTN; size <<= 1){
    int stride = size >> 1;
    while (stride >= 8192){
      int ns = 1;
      while (ns < 4 && (stride >> ns) >= 8192) ns++;
      switch (ns){
        case 1: k_bpassM<1><<<SORTN/2/256,  256, 0, stream>>>(keys, size, stride); break;
        case 2: k_bpassM<2><<<SORTN/4/256,  256, 0, stream>>>(keys, size, stride); break;
        case 3: k_bpassM<3><<<SORTN/8/256,  256, 0, stream>>>(keys, size, stride); break;
        default:k_bpassM<4><<<SORTN/16/256, 256, 0, stream>>>(keys, size, stride); break;
      }
      stride >>= ns;
    }
    k_bmerge_local8k<<<SORTN/8192, 1024, 0, stream>>>(keys, size);
  }

  // f64 band refinement around the cutoff
  kr_cut     <<<1, 64, 0, stream>>>(keys, k, cutbuf, r01);
  kr_rescore <<<2*BAND_W, 256, 0, stream>>>(keys, s32, x, deg, wS1,bS1,wS2,bS2,
                                            wF1,bF1,wF2,bF2, s1b, scal,
                                            cutbuf, r01, bandS, k, N);
  kr_bandsort<<<1, 1024, 0, stream>>>(keys, bandS, r01, k);

  k_finalize<<<(k+255)/256, 256, 0, stream>>>(keys, s32, k, nmap, outS);
  k_xpool_mfma<<<(k+63)/64, 512, 0, stream>>>(x, keys, wswPH, wswPL, bP, outX, k);
  k_ecount  <<<nblk_e, 256, 0, stream>>>(ei, ei+E, nmap, E, bcount);
  k_escan   <<<1, 1024, 0, stream>>>(bcount, nblk_e, boff, tot);
  k_efill_tail<<<1024, 256, 0, stream>>>(outER, outEC, tot, E);
  k_escatter<<<nblk_e, 256, 0, stream>>>(ei, ei+E, nmap, E, boff, outER, outEC);
}